// Round 1
// baseline (787.756 us; speedup 1.0000x reference)
//
#include <hip/hip_runtime.h>
#include <hip/hip_bf16.h>
#include <stdint.h>

// RelationMultiHeadAttention on MI355X.
// Pipeline: k_prep (weightsT->bf16, pre-swizzled) -> k_proj x3 (qh, kh*scale, vhT)
//           -> k_qt (qt = qh @ Wrk^T) -> k_attn (per (b,m): s2+s1+softmax+arv+val1+val2)
//           -> k_out (out = VAL @ Wo^T + bo, fp32)
// brk dropped (softmax-invariant); brv added via att-sums-to-1 identity.

typedef __attribute__((ext_vector_type(4))) float f32x4;
typedef __attribute__((ext_vector_type(8))) short s16x8;

#define MFMA16(A, B, C) __builtin_amdgcn_mfma_f32_16x16x32_bf16(A, B, C, 0, 0, 0)

__device__ __forceinline__ uint16_t f2bf(float x) {
  uint32_t u = __float_as_uint(x);
  u += 0x7fffu + ((u >> 16) & 1u);   // RNE; inputs are finite
  return (uint16_t)(u >> 16);
}

__device__ __forceinline__ s16x8 pack8(float4 a, float4 b) {
  s16x8 r;
  r[0] = (short)f2bf(a.x); r[1] = (short)f2bf(a.y); r[2] = (short)f2bf(a.z); r[3] = (short)f2bf(a.w);
  r[4] = (short)f2bf(b.x); r[5] = (short)f2bf(b.y); r[6] = (short)f2bf(b.z); r[7] = (short)f2bf(b.w);
  return r;
}

// ---------------------------------------------------------------------------
// K0: weight prep. z=0..3: W[1024,1024] -> WT_sw bf16 [n][k] with per-row
// 16B-chunk XOR swizzle (chunk ^= n&7, low-3 bits) so GEMM LDS staging is a
// linear copy and ds_read_b128 fragments are bank-conflict-light.
// z=4 (block 0 only): WrkB bf16 cast, WrvT bf16 transpose.
// ---------------------------------------------------------------------------
__global__ __launch_bounds__(256) void k_prep(
    const float* __restrict__ Wq, const float* __restrict__ Wk,
    const float* __restrict__ Wv, const float* __restrict__ Wo,
    const float* __restrict__ Wrk, const float* __restrict__ Wrv,
    uint16_t* __restrict__ WqT, uint16_t* __restrict__ WkT,
    uint16_t* __restrict__ WvT, uint16_t* __restrict__ WoT,
    uint16_t* __restrict__ WrkB, uint16_t* __restrict__ WrvT) {
  int z = blockIdx.y;
  int t = threadIdx.x;
  if (z == 4) {
    if (blockIdx.x == 0) {
      for (int i = t; i < 128 * 64; i += 256) WrkB[i] = f2bf(Wrk[i]);
      for (int i = t; i < 64 * 128; i += 256) {
        int d = i >> 7, r = i & 127;
        WrvT[i] = f2bf(Wrv[r * 64 + d]);
      }
    }
    return;
  }
  const float* W = (z == 0) ? Wq : (z == 1) ? Wk : (z == 2) ? Wv : Wo;
  uint16_t* O = (z == 0) ? WqT : (z == 1) ? WkT : (z == 2) ? WvT : WoT;
  int tk = (blockIdx.x >> 4) * 64;
  int tn = (blockIdx.x & 15) * 64;
  __shared__ float tile[64][65];
  {
    int kk = t >> 2, c0 = (t & 3) * 16;
    const float* src = W + (size_t)(tk + kk) * 1024 + tn + c0;
#pragma unroll
    for (int i = 0; i < 16; i += 4) {
      float4 v = *(const float4*)(src + i);
      tile[kk][c0 + i + 0] = v.x; tile[kk][c0 + i + 1] = v.y;
      tile[kk][c0 + i + 2] = v.z; tile[kk][c0 + i + 3] = v.w;
    }
  }
  __syncthreads();
  {
    int n_loc = t >> 2;
    int n = tn + n_loc;
#pragma unroll
    for (int cc = 0; cc < 2; ++cc) {
      int c = (t & 3) * 2 + cc;       // local chunk 0..7 in this k-window
      int csrc = c ^ (n & 7);         // swizzle source chunk
      s16x8 pk;
#pragma unroll
      for (int j = 0; j < 8; ++j) pk[j] = (short)f2bf(tile[csrc * 8 + j][n_loc]);
      *reinterpret_cast<s16x8*>(O + (size_t)n * 1024 + tk + c * 8) = pk;
    }
  }
}

// ---------------------------------------------------------------------------
// K1: Y = X@W + b, X fp32 [2048,1024], WT_sw bf16 (pre-transposed+swizzled).
// mode 0: qh bf16 [2048,1024]
// mode 1: kh bf16 [2048,1024] scaled by 1/8 (score_1 scale baked in)
// mode 2: vhT bf16 [B,H,64,512] (n-contiguous, for val1 B-fragments)
// BM=BN=128, BK=64, 4 waves in 2x2 of 64x64 each.
// ---------------------------------------------------------------------------
__global__ __launch_bounds__(256) void k_proj(
    const float* __restrict__ X, const uint16_t* __restrict__ WT,
    const float* __restrict__ bias, uint16_t* __restrict__ out, int mode) {
  __shared__ alignas(16) uint16_t As[128 * 64];
  __shared__ alignas(16) uint16_t Bs[128 * 64];
  int t = threadIdx.x, lane = t & 63, w = t >> 6, lr = lane & 15, lg = lane >> 4;
  int m0 = blockIdx.x * 128, n0 = blockIdx.y * 128;
  int wm = (w >> 1) * 64, wn = (w & 1) * 64;
  f32x4 acc[4][4];
#pragma unroll
  for (int i = 0; i < 4; ++i)
#pragma unroll
    for (int j = 0; j < 4; ++j) acc[i][j] = (f32x4){0.f, 0.f, 0.f, 0.f};
  int srow = t >> 1, sh = t & 1;
  for (int ko = 0; ko < 16; ++ko) {
    __syncthreads();
    {
      const float* src = X + (size_t)(m0 + srow) * 1024 + ko * 64 + sh * 32;
#pragma unroll
      for (int c = 0; c < 4; ++c) {
        float4 v0 = *(const float4*)(src + c * 8);
        float4 v1 = *(const float4*)(src + c * 8 + 4);
        s16x8 pk = pack8(v0, v1);
        *reinterpret_cast<s16x8*>((char*)As + srow * 128 +
                                  ((((sh * 4 + c) * 16)) ^ ((srow & 7) << 4))) = pk;
      }
      const uint16_t* bsrc = WT + (size_t)(n0 + srow) * 1024 + ko * 64 + sh * 32;
#pragma unroll
      for (int c = 0; c < 4; ++c) {
        s16x8 vb = *(const s16x8*)(bsrc + c * 8);
        *reinterpret_cast<s16x8*>((char*)Bs + srow * 128 + (sh * 4 + c) * 16) = vb;
      }
    }
    __syncthreads();
#pragma unroll
    for (int kk = 0; kk < 2; ++kk) {
      s16x8 af[4], bf[4];
#pragma unroll
      for (int mt = 0; mt < 4; ++mt) {
        int row = wm + mt * 16 + lr;
        af[mt] = *(const s16x8*)((const char*)As + row * 128 +
                                 (((kk * 32 + lg * 8) * 2) ^ ((row & 7) << 4)));
      }
#pragma unroll
      for (int nt = 0; nt < 4; ++nt) {
        int row = wn + nt * 16 + lr;
        bf[nt] = *(const s16x8*)((const char*)Bs + row * 128 +
                                 (((kk * 32 + lg * 8) * 2) ^ ((row & 7) << 4)));
      }
#pragma unroll
      for (int mt = 0; mt < 4; ++mt)
#pragma unroll
        for (int nt = 0; nt < 4; ++nt)
          acc[mt][nt] = MFMA16(af[mt], bf[nt], acc[mt][nt]);
    }
  }
  float sc = (mode == 1) ? 0.125f : 1.0f;
#pragma unroll
  for (int mt = 0; mt < 4; ++mt) {
#pragma unroll
    for (int nt = 0; nt < 4; ++nt) {
      int col = n0 + wn + nt * 16 + lr;
      float bcol = bias[col];
      if (mode != 2) {
#pragma unroll
        for (int r = 0; r < 4; ++r) {
          int row = m0 + wm + mt * 16 + lg * 4 + r;
          out[(size_t)row * 1024 + col] = f2bf((acc[mt][nt][r] + bcol) * sc);
        }
      } else {
        int row0 = m0 + wm + mt * 16 + lg * 4;  // sequence position base
        int b = row0 >> 9, n = row0 & 511;
        int h = col >> 6, d = col & 63;
        ushort4 pk;
        pk.x = f2bf(acc[mt][nt][0] + bcol);
        pk.y = f2bf(acc[mt][nt][1] + bcol);
        pk.z = f2bf(acc[mt][nt][2] + bcol);
        pk.w = f2bf(acc[mt][nt][3] + bcol);
        *reinterpret_cast<ushort4*>(out + ((size_t)(b * 16 + h) * 64 + d) * 512 + n) = pk;
      }
    }
  }
}

// ---------------------------------------------------------------------------
// K1b: qt[32768,128] = qh (viewed [32768,64]) @ WrkB^T. K=64, direct-global frags.
// row = bm*16 + h; output layout = [B,M,H,DR] (contiguous per (b,m)).
// ---------------------------------------------------------------------------
__global__ __launch_bounds__(256) void k_qt(
    const uint16_t* __restrict__ qh, const uint16_t* __restrict__ WrkB,
    uint16_t* __restrict__ qt) {
  int t = threadIdx.x, lane = t & 63, w = t >> 6, lr = lane & 15, lg = lane >> 4;
  int row0 = blockIdx.x * 64 + w * 16;
  f32x4 acc[8];
#pragma unroll
  for (int i = 0; i < 8; ++i) acc[i] = (f32x4){0.f, 0.f, 0.f, 0.f};
  s16x8 af[2];
#pragma unroll
  for (int kk = 0; kk < 2; ++kk)
    af[kk] = *(const s16x8*)(qh + (size_t)(row0 + lr) * 64 + kk * 32 + lg * 8);
#pragma unroll
  for (int rt = 0; rt < 8; ++rt) {
#pragma unroll
    for (int kk = 0; kk < 2; ++kk) {
      s16x8 bf = *(const s16x8*)(WrkB + (size_t)(rt * 16 + lr) * 64 + kk * 32 + lg * 8);
      acc[rt] = MFMA16(af[kk], bf, acc[rt]);
    }
  }
#pragma unroll
  for (int rt = 0; rt < 8; ++rt)
#pragma unroll
    for (int r = 0; r < 4; ++r)
      qt[(size_t)(row0 + lg * 4 + r) * 128 + rt * 16 + lr] = f2bf(acc[rt][r]);
}

// ---------------------------------------------------------------------------
// K3: per-(b,m) fused attention. 2048 WGs x 256 threads (4 waves).
// Wave w owns n in [w*128, w*128+128) for scores; r-cols [w*32,w*32+32) for arv;
// d-tile [w*16,w*16+16) for val.
// ---------------------------------------------------------------------------
__global__ __launch_bounds__(256) void k_attn(
    const uint16_t* __restrict__ qh, const uint16_t* __restrict__ kh,
    const uint16_t* __restrict__ vhT, const uint16_t* __restrict__ qt,
    const float* __restrict__ rk, const float* __restrict__ rv,
    const uint16_t* __restrict__ WrvT, const float* __restrict__ brv,
    uint16_t* __restrict__ VAL) {
  // XCD swizzle: each XCD gets a contiguous bm range (one batch's kh/vhT in its L2)
  int bm = (blockIdx.x & 7) * 256 + (blockIdx.x >> 3);
  int b = bm >> 9;
  int t = threadIdx.x, lane = t & 63, w = t >> 6, lr = lane & 15, lg = lane >> 4;
  __shared__ alignas(16) uint16_t qh_lds[16 * 64];
  __shared__ alignas(16) uint16_t att_lds[16 * 512];  // swizzled rows of 1KB
  __shared__ alignas(16) uint16_t arv_lds[16 * 128];  // swizzled rows of 256B
  __shared__ float red[2][16][4];
  const s16x8 z8 = {0, 0, 0, 0, 0, 0, 0, 0};

  for (int i = t; i < 1024; i += 256) qh_lds[i] = qh[(size_t)bm * 1024 + i];

  s16x8 aqt[4];
#pragma unroll
  for (int kk = 0; kk < 4; ++kk)
    aqt[kk] = *(const s16x8*)(qt + ((size_t)bm * 16 + lr) * 128 + kk * 32 + lg * 8);

  f32x4 acc[8];
#pragma unroll
  for (int j = 0; j < 8; ++j) acc[j] = (f32x4){0.f, 0.f, 0.f, 0.f};
  __syncthreads();

  int wn = w * 128;
  // ---- phase 1: score_2 = qt . r_k  (fp32 stream, cvt to bf16, direct B-frags)
  const float* rkb = rk + (size_t)bm * 65536;
#pragma unroll 2
  for (int j = 0; j < 8; ++j) {
    const float* rowp = rkb + (size_t)(wn + j * 16 + lr) * 128 + lg * 8;
#pragma unroll
    for (int kk = 0; kk < 4; ++kk) {
      float4 v0 = *(const float4*)(rowp + kk * 32);
      float4 v1 = *(const float4*)(rowp + kk * 32 + 4);
      acc[j] = MFMA16(aqt[kk], pack8(v0, v1), acc[j]);
    }
  }
  // ---- phase 2: score_1 via block-diagonal sparse-A MFMA over kh (scale baked in kh)
  const uint16_t* khb = kh + (size_t)b * 512 * 1024;
  for (int kk = 0; kk < 32; ++kk) {
    s16x8 a = *(const s16x8*)(qh_lds + (kk >> 1) * 64 + (kk & 1) * 32 + lg * 8);
    s16x8 az = (lr == (kk >> 1)) ? a : z8;
#pragma unroll
    for (int j = 0; j < 8; ++j) {
      s16x8 bf = *(const s16x8*)(khb + (size_t)(wn + j * 16 + lr) * 1024 + kk * 32 + lg * 8);
      acc[j] = MFMA16(az, bf, acc[j]);
    }
  }
  // ---- phase 3: softmax (rows h = lg*4+r, cols n)
  float mrow[4], inv[4];
#pragma unroll
  for (int r = 0; r < 4; ++r) {
    float mx = acc[0][r];
#pragma unroll
    for (int j = 1; j < 8; ++j) mx = fmaxf(mx, acc[j][r]);
#pragma unroll
    for (int off = 1; off < 16; off <<= 1) mx = fmaxf(mx, __shfl_xor(mx, off, 64));
    mrow[r] = mx;
  }
  if (lr == 0) {
#pragma unroll
    for (int r = 0; r < 4; ++r) red[0][lg * 4 + r][w] = mrow[r];
  }
  __syncthreads();
#pragma unroll
  for (int r = 0; r < 4; ++r) {
    const float* p = red[0][lg * 4 + r];
    mrow[r] = fmaxf(fmaxf(p[0], p[1]), fmaxf(p[2], p[3]));
  }
#pragma unroll
  for (int r = 0; r < 4; ++r) {
    float s = 0.f;
#pragma unroll
    for (int j = 0; j < 8; ++j) {
      float pj = __expf(acc[j][r] - mrow[r]);
      acc[j][r] = pj;
      s += pj;
    }
#pragma unroll
    for (int off = 1; off < 16; off <<= 1) s += __shfl_xor(s, off, 64);
    inv[r] = s;
  }
  if (lr == 0) {
#pragma unroll
    for (int r = 0; r < 4; ++r) red[1][lg * 4 + r][w] = inv[r];
  }
  __syncthreads();
#pragma unroll
  for (int r = 0; r < 4; ++r) {
    const float* p = red[1][lg * 4 + r];
    inv[r] = 1.f / (p[0] + p[1] + p[2] + p[3]);
  }
#pragma unroll
  for (int r = 0; r < 4; ++r) {
    int h = lg * 4 + r;
#pragma unroll
    for (int j = 0; j < 8; ++j) {
      int n = wn + j * 16 + lr;
      uint32_t off = (uint32_t)h * 1024 + (((uint32_t)n * 2) ^ ((uint32_t)(h & 7) << 4));
      *(uint16_t*)((char*)att_lds + off) = f2bf(acc[j][r] * inv[r]);
    }
  }
  __syncthreads();
  // ---- phase 4a: arv[h, r] = sum_n att[h,n] * r_v[m,n,r]  (wave owns 32 r-cols)
  f32x4 arv0 = (f32x4){0.f, 0.f, 0.f, 0.f}, arv1 = arv0;
  const float* rvb = rv + (size_t)bm * 65536;
  for (int kk = 0; kk < 16; ++kk) {
    int nb = kk * 32 + lg * 8;
    s16x8 a = *(const s16x8*)((const char*)att_lds + lr * 1024 +
                              (((uint32_t)nb * 2) ^ ((uint32_t)(lr & 7) << 4)));
#pragma unroll
    for (int rt = 0; rt < 2; ++rt) {
      int rc = w * 32 + rt * 16 + lr;
      s16x8 bf;
#pragma unroll
      for (int i = 0; i < 8; ++i) bf[i] = (short)f2bf(rvb[(size_t)(nb + i) * 128 + rc]);
      if (rt == 0) arv0 = MFMA16(a, bf, arv0);
      else         arv1 = MFMA16(a, bf, arv1);
    }
  }
  // ---- phase 4b: val1 via block-diagonal sparse-A MFMA over vhT (wave owns d-tile)
  f32x4 vacc = (f32x4){0.f, 0.f, 0.f, 0.f};
  const uint16_t* vtb = vhT + (size_t)b * 1024 * 512;
  for (int nk = 0; nk < 16; ++nk) {
    int nb = nk * 32 + lg * 8;
    s16x8 a = *(const s16x8*)((const char*)att_lds + lr * 1024 +
                              (((uint32_t)nb * 2) ^ ((uint32_t)(lr & 7) << 4)));
#pragma unroll
    for (int hp = 0; hp < 16; ++hp) {
      s16x8 az = (lr == hp) ? a : z8;
      s16x8 bf = *(const s16x8*)(vtb + (size_t)(hp * 64 + w * 16 + lr) * 512 + nb);
      vacc = MFMA16(az, bf, vacc);
    }
  }
  // ---- phase 5: arv -> LDS (bf16, swizzled)
#pragma unroll
  for (int r = 0; r < 4; ++r) {
    int h = lg * 4 + r;
    uint32_t rc0 = (uint32_t)(w * 32 + lr) * 2;
    uint32_t rc1 = (uint32_t)(w * 32 + 16 + lr) * 2;
    *(uint16_t*)((char*)arv_lds + h * 256 + (rc0 ^ ((uint32_t)(h & 7) << 4))) = f2bf(arv0[r]);
    *(uint16_t*)((char*)arv_lds + h * 256 + (rc1 ^ ((uint32_t)(h & 7) << 4))) = f2bf(arv1[r]);
  }
  __syncthreads();
  // ---- phase 6: val2 = arv @ Wrv (+brv), accumulated into vacc
#pragma unroll
  for (int kk = 0; kk < 4; ++kk) {
    uint32_t rb = (uint32_t)(kk * 32 + lg * 8) * 2;
    s16x8 a = *(const s16x8*)((const char*)arv_lds + lr * 256 +
                              (rb ^ ((uint32_t)(lr & 7) << 4)));
    s16x8 bf = *(const s16x8*)(WrvT + (size_t)(w * 16 + lr) * 128 + kk * 32 + lg * 8);
    vacc = MFMA16(a, bf, vacc);
  }
  float bias = brv[w * 16 + lr];
#pragma unroll
  for (int r = 0; r < 4; ++r)
    VAL[(size_t)bm * 1024 + (lg * 4 + r) * 64 + w * 16 + lr] = f2bf(vacc[r] + bias);
}

// ---------------------------------------------------------------------------
// K5: out = VAL @ Wo + bo (fp32 out). Same structure as k_proj, bf16 A.
// ---------------------------------------------------------------------------
__global__ __launch_bounds__(256) void k_out(
    const uint16_t* __restrict__ A, const uint16_t* __restrict__ WT,
    const float* __restrict__ bias, float* __restrict__ out) {
  __shared__ alignas(16) uint16_t As[128 * 64];
  __shared__ alignas(16) uint16_t Bs[128 * 64];
  int t = threadIdx.x, lane = t & 63, w = t >> 6, lr = lane & 15, lg = lane >> 4;
  int m0 = blockIdx.x * 128, n0 = blockIdx.y * 128;
  int wm = (w >> 1) * 64, wn = (w & 1) * 64;
  f32x4 acc[4][4];
#pragma unroll
  for (int i = 0; i < 4; ++i)
#pragma unroll
    for (int j = 0; j < 4; ++j) acc[i][j] = (f32x4){0.f, 0.f, 0.f, 0.f};
  int srow = t >> 1, sh = t & 1;
  for (int ko = 0; ko < 16; ++ko) {
    __syncthreads();
    {
      const uint16_t* asrc = A + (size_t)(m0 + srow) * 1024 + ko * 64 + sh * 32;
      const uint16_t* bsrc = WT + (size_t)(n0 + srow) * 1024 + ko * 64 + sh * 32;
#pragma unroll
      for (int c = 0; c < 4; ++c) {
        s16x8 va = *(const s16x8*)(asrc + c * 8);
        *reinterpret_cast<s16x8*>((char*)As + srow * 128 +
                                  ((((sh * 4 + c) * 16)) ^ ((srow & 7) << 4))) = va;
        s16x8 vb = *(const s16x8*)(bsrc + c * 8);
        *reinterpret_cast<s16x8*>((char*)Bs + srow * 128 + (sh * 4 + c) * 16) = vb;
      }
    }
    __syncthreads();
#pragma unroll
    for (int kk = 0; kk < 2; ++kk) {
      s16x8 af[4], bf[4];
#pragma unroll
      for (int mt = 0; mt < 4; ++mt) {
        int row = wm + mt * 16 + lr;
        af[mt] = *(const s16x8*)((const char*)As + row * 128 +
                                 (((kk * 32 + lg * 8) * 2) ^ ((row & 7) << 4)));
      }
#pragma unroll
      for (int nt = 0; nt < 4; ++nt) {
        int row = wn + nt * 16 + lr;
        bf[nt] = *(const s16x8*)((const char*)Bs + row * 128 +
                                 (((kk * 32 + lg * 8) * 2) ^ ((row & 7) << 4)));
      }
#pragma unroll
      for (int mt = 0; mt < 4; ++mt)
#pragma unroll
        for (int nt = 0; nt < 4; ++nt)
          acc[mt][nt] = MFMA16(af[mt], bf[nt], acc[mt][nt]);
    }
  }
#pragma unroll
  for (int mt = 0; mt < 4; ++mt) {
#pragma unroll
    for (int nt = 0; nt < 4; ++nt) {
      int col = n0 + wn + nt * 16 + lr;
      float bcol = bias[col];
#pragma unroll
      for (int r = 0; r < 4; ++r) {
        int row = m0 + wm + mt * 16 + lg * 4 + r;
        out[(size_t)row * 1024 + col] = acc[mt][nt][r] + bcol;
      }
    }
  }
}

// ---------------------------------------------------------------------------
extern "C" void kernel_launch(void* const* d_in, const int* in_sizes, int n_in,
                              void* d_out, int out_size, void* d_ws, size_t ws_size,
                              hipStream_t stream) {
  const float* q   = (const float*)d_in[0];
  const float* k_  = (const float*)d_in[1];
  const float* v   = (const float*)d_in[2];
  const float* r_k = (const float*)d_in[3];
  const float* r_v = (const float*)d_in[4];
  const float* Wq  = (const float*)d_in[5];
  const float* bq  = (const float*)d_in[6];
  const float* Wk  = (const float*)d_in[7];
  const float* bk  = (const float*)d_in[8];
  const float* Wv  = (const float*)d_in[9];
  const float* bv  = (const float*)d_in[10];
  const float* Wrk = (const float*)d_in[11];
  // d_in[12] = brk: softmax-invariant, unused
  const float* Wrv = (const float*)d_in[13];
  const float* brv = (const float*)d_in[14];
  const float* Wo  = (const float*)d_in[15];
  const float* bo  = (const float*)d_in[16];
  (void)in_sizes; (void)n_in; (void)out_size;

  char* ws = (char*)d_ws;
  uint16_t* WqT  = (uint16_t*)(ws + (size_t)(0));
  uint16_t* WkT  = (uint16_t*)(ws + (size_t)(2u << 20));
  uint16_t* WvT  = (uint16_t*)(ws + (size_t)(4u << 20));
  uint16_t* WoT  = (uint16_t*)(ws + (size_t)(6u << 20));
  uint16_t* WrkB = (uint16_t*)(ws + (size_t)(8u << 20));
  uint16_t* WrvT = (uint16_t*)(ws + (size_t)(8u << 20) + (64u << 10));
  uint16_t* QH   = (uint16_t*)(ws + (size_t)(16u << 20));
  uint16_t* KH   = (uint16_t*)(ws + (size_t)(20u << 20));
  uint16_t* VHT  = (uint16_t*)(ws + (size_t)(24u << 20));
  uint16_t* QT   = (uint16_t*)(ws + (size_t)(28u << 20));
  uint16_t* VALB = (uint16_t*)(ws + (size_t)(36u << 20));
  if (ws_size < (size_t)(40u << 20)) return;  // need 40 MB of scratch

  dim3 blk(256, 1, 1);
  k_prep<<<dim3(256, 5, 1), blk, 0, stream>>>(Wq, Wk, Wv, Wo, Wrk, Wrv,
                                              WqT, WkT, WvT, WoT, WrkB, WrvT);
  k_proj<<<dim3(16, 8, 1), blk, 0, stream>>>(q,  WqT, bq, QH,  0);
  k_proj<<<dim3(16, 8, 1), blk, 0, stream>>>(k_, WkT, bk, KH,  1);
  k_proj<<<dim3(16, 8, 1), blk, 0, stream>>>(v,  WvT, bv, VHT, 2);
  k_qt<<<dim3(512, 1, 1), blk, 0, stream>>>(QH, WrkB, QT);
  k_attn<<<dim3(2048, 1, 1), blk, 0, stream>>>(QH, KH, VHT, QT, r_k, r_v,
                                               WrvT, brv, VALB);
  k_out<<<dim3(16, 8, 1), blk, 0, stream>>>(VALB, WoT, bo, (float*)d_out);
}

// Round 2
// 724.330 us; speedup vs baseline: 1.0876x; 1.0876x over previous
//
#include <hip/hip_runtime.h>
#include <hip/hip_bf16.h>
#include <stdint.h>

// RelationMultiHeadAttention on MI355X.
// Pipeline: k_prep (weightsT->bf16, pre-swizzled) -> k_projqkv (qh, kh*scale, vhT)
//           -> k_qt (qt = qh @ Wrk^T) -> k_attn (per (b,m): s2+s1+softmax+val1+arv+val2)
//           -> k_out (out = VAL @ Wo^T + bo, fp32)
// brk dropped (softmax-invariant); brv added via att-sums-to-1 identity.

typedef __attribute__((ext_vector_type(4))) float f32x4;
typedef __attribute__((ext_vector_type(8))) short s16x8;

#define MFMA16(A, B, C) __builtin_amdgcn_mfma_f32_16x16x32_bf16(A, B, C, 0, 0, 0)

__device__ __forceinline__ uint16_t f2bf(float x) {
  uint32_t u = __float_as_uint(x);
  u += 0x7fffu + ((u >> 16) & 1u);   // RNE; inputs are finite
  return (uint16_t)(u >> 16);
}

__device__ __forceinline__ s16x8 pack8(float4 a, float4 b) {
  s16x8 r;
  r[0] = (short)f2bf(a.x); r[1] = (short)f2bf(a.y); r[2] = (short)f2bf(a.z); r[3] = (short)f2bf(a.w);
  r[4] = (short)f2bf(b.x); r[5] = (short)f2bf(b.y); r[6] = (short)f2bf(b.z); r[7] = (short)f2bf(b.w);
  return r;
}

// ---------------------------------------------------------------------------
// K0: weight prep. z=0..3: W[1024,1024] -> WT_sw bf16 [n][k] with per-row
// 16B-chunk XOR swizzle (chunk ^= n&7) so GEMM LDS staging is a linear copy
// and ds_read_b128 fragments are bank-conflict-light.
// z=4 (block 0 only): WrkB bf16 cast, WrvT bf16 transpose.
// ---------------------------------------------------------------------------
__global__ __launch_bounds__(256) void k_prep(
    const float* __restrict__ Wq, const float* __restrict__ Wk,
    const float* __restrict__ Wv, const float* __restrict__ Wo,
    const float* __restrict__ Wrk, const float* __restrict__ Wrv,
    uint16_t* __restrict__ WqT, uint16_t* __restrict__ WkT,
    uint16_t* __restrict__ WvT, uint16_t* __restrict__ WoT,
    uint16_t* __restrict__ WrkB, uint16_t* __restrict__ WrvT) {
  int z = blockIdx.y;
  int t = threadIdx.x;
  if (z == 4) {
    if (blockIdx.x == 0) {
      for (int i = t; i < 128 * 64; i += 256) WrkB[i] = f2bf(Wrk[i]);
      for (int i = t; i < 64 * 128; i += 256) {
        int d = i >> 7, r = i & 127;
        WrvT[i] = f2bf(Wrv[r * 64 + d]);
      }
    }
    return;
  }
  const float* W = (z == 0) ? Wq : (z == 1) ? Wk : (z == 2) ? Wv : Wo;
  uint16_t* O = (z == 0) ? WqT : (z == 1) ? WkT : (z == 2) ? WvT : WoT;
  int tk = (blockIdx.x >> 4) * 64;
  int tn = (blockIdx.x & 15) * 64;
  __shared__ float tile[64][65];
  {
    int kk = t >> 2, c0 = (t & 3) * 16;
    const float* src = W + (size_t)(tk + kk) * 1024 + tn + c0;
#pragma unroll
    for (int i = 0; i < 16; i += 4) {
      float4 v = *(const float4*)(src + i);
      tile[kk][c0 + i + 0] = v.x; tile[kk][c0 + i + 1] = v.y;
      tile[kk][c0 + i + 2] = v.z; tile[kk][c0 + i + 3] = v.w;
    }
  }
  __syncthreads();
  {
    int n_loc = t >> 2;
    int n = tn + n_loc;
#pragma unroll
    for (int cc = 0; cc < 2; ++cc) {
      int c = (t & 3) * 2 + cc;       // local chunk 0..7 in this k-window
      int csrc = c ^ (n & 7);         // swizzle source chunk
      s16x8 pk;
#pragma unroll
      for (int j = 0; j < 8; ++j) pk[j] = (short)f2bf(tile[csrc * 8 + j][n_loc]);
      *reinterpret_cast<s16x8*>(O + (size_t)n * 1024 + tk + c * 8) = pk;
    }
  }
}

// ---------------------------------------------------------------------------
// K1: Y = X@W + b for q,k,v in one launch (blockIdx.z = mode).
// mode 0: qh bf16 [2048,1024]
// mode 1: kh bf16 [2048,1024] scaled by 1/8 (score_1 scale baked in)
// mode 2: vhT bf16 [B,H,64,512] (n-contiguous, for val1 B-fragments)
// BM=BN=128, BK=64, 4 waves in 2x2 of 64x64 each.
// ---------------------------------------------------------------------------
__global__ __launch_bounds__(256) void k_projqkv(
    const float* __restrict__ Xq, const float* __restrict__ Xk,
    const float* __restrict__ Xv, const uint16_t* __restrict__ WTbase,
    const float* __restrict__ bq, const float* __restrict__ bk,
    const float* __restrict__ bv, uint16_t* __restrict__ outbase) {
  int mode = blockIdx.z;
  const float* X = (mode == 0) ? Xq : (mode == 1) ? Xk : Xv;
  const float* bias = (mode == 0) ? bq : (mode == 1) ? bk : bv;
  const uint16_t* WT = WTbase + (size_t)mode * (1u << 20);
  uint16_t* out = outbase + (size_t)mode * (2u << 20);

  __shared__ alignas(16) uint16_t As[128 * 64];
  __shared__ alignas(16) uint16_t Bs[128 * 64];
  int t = threadIdx.x, lane = t & 63, w = t >> 6, lr = lane & 15, lg = lane >> 4;
  int m0 = blockIdx.x * 128, n0 = blockIdx.y * 128;
  int wm = (w >> 1) * 64, wn = (w & 1) * 64;
  f32x4 acc[4][4];
#pragma unroll
  for (int i = 0; i < 4; ++i)
#pragma unroll
    for (int j = 0; j < 4; ++j) acc[i][j] = (f32x4){0.f, 0.f, 0.f, 0.f};
  int srow = t >> 1, sh = t & 1;
  for (int ko = 0; ko < 16; ++ko) {
    __syncthreads();
    {
      const float* src = X + (size_t)(m0 + srow) * 1024 + ko * 64 + sh * 32;
#pragma unroll
      for (int c = 0; c < 4; ++c) {
        float4 v0 = *(const float4*)(src + c * 8);
        float4 v1 = *(const float4*)(src + c * 8 + 4);
        s16x8 pk = pack8(v0, v1);
        *reinterpret_cast<s16x8*>((char*)As + srow * 128 +
                                  ((((sh * 4 + c) * 16)) ^ ((srow & 7) << 4))) = pk;
      }
      const uint16_t* bsrc = WT + (size_t)(n0 + srow) * 1024 + ko * 64 + sh * 32;
#pragma unroll
      for (int c = 0; c < 4; ++c) {
        s16x8 vb = *(const s16x8*)(bsrc + c * 8);
        *reinterpret_cast<s16x8*>((char*)Bs + srow * 128 + (sh * 4 + c) * 16) = vb;
      }
    }
    __syncthreads();
#pragma unroll
    for (int kk = 0; kk < 2; ++kk) {
      s16x8 af[4], bf[4];
#pragma unroll
      for (int mt = 0; mt < 4; ++mt) {
        int row = wm + mt * 16 + lr;
        af[mt] = *(const s16x8*)((const char*)As + row * 128 +
                                 (((kk * 32 + lg * 8) * 2) ^ ((row & 7) << 4)));
      }
#pragma unroll
      for (int nt = 0; nt < 4; ++nt) {
        int row = wn + nt * 16 + lr;
        bf[nt] = *(const s16x8*)((const char*)Bs + row * 128 +
                                 (((kk * 32 + lg * 8) * 2) ^ ((row & 7) << 4)));
      }
#pragma unroll
      for (int mt = 0; mt < 4; ++mt)
#pragma unroll
        for (int nt = 0; nt < 4; ++nt)
          acc[mt][nt] = MFMA16(af[mt], bf[nt], acc[mt][nt]);
    }
  }
  float sc = (mode == 1) ? 0.125f : 1.0f;
#pragma unroll
  for (int mt = 0; mt < 4; ++mt) {
#pragma unroll
    for (int nt = 0; nt < 4; ++nt) {
      int col = n0 + wn + nt * 16 + lr;
      float bcol = bias[col];
      if (mode != 2) {
#pragma unroll
        for (int r = 0; r < 4; ++r) {
          int row = m0 + wm + mt * 16 + lg * 4 + r;
          out[(size_t)row * 1024 + col] = f2bf((acc[mt][nt][r] + bcol) * sc);
        }
      } else {
        int row0 = m0 + wm + mt * 16 + lg * 4;  // sequence position base
        int b = row0 >> 9, n = row0 & 511;
        int h = col >> 6, d = col & 63;
        ushort4 pk;
        pk.x = f2bf(acc[mt][nt][0] + bcol);
        pk.y = f2bf(acc[mt][nt][1] + bcol);
        pk.z = f2bf(acc[mt][nt][2] + bcol);
        pk.w = f2bf(acc[mt][nt][3] + bcol);
        *reinterpret_cast<ushort4*>(out + ((size_t)(b * 16 + h) * 64 + d) * 512 + n) = pk;
      }
    }
  }
}

// ---------------------------------------------------------------------------
// K1b: qt[32768,128] = qh (viewed [32768,64]) @ WrkB^T. K=64, direct-global frags.
// row = bm*16 + h; output layout = [B,M,H,DR] (contiguous per (b,m)).
// ---------------------------------------------------------------------------
__global__ __launch_bounds__(256) void k_qt(
    const uint16_t* __restrict__ qh, const uint16_t* __restrict__ WrkB,
    uint16_t* __restrict__ qt) {
  int t = threadIdx.x, lane = t & 63, w = t >> 6, lr = lane & 15, lg = lane >> 4;
  int row0 = blockIdx.x * 64 + w * 16;
  f32x4 acc[8];
#pragma unroll
  for (int i = 0; i < 8; ++i) acc[i] = (f32x4){0.f, 0.f, 0.f, 0.f};
  s16x8 af[2];
#pragma unroll
  for (int kk = 0; kk < 2; ++kk)
    af[kk] = *(const s16x8*)(qh + (size_t)(row0 + lr) * 64 + kk * 32 + lg * 8);
#pragma unroll
  for (int rt = 0; rt < 8; ++rt) {
#pragma unroll
    for (int kk = 0; kk < 2; ++kk) {
      s16x8 bf = *(const s16x8*)(WrkB + (size_t)(rt * 16 + lr) * 64 + kk * 32 + lg * 8);
      acc[rt] = MFMA16(af[kk], bf, acc[rt]);
    }
  }
#pragma unroll
  for (int rt = 0; rt < 8; ++rt)
#pragma unroll
    for (int r = 0; r < 4; ++r)
      qt[(size_t)(row0 + lg * 4 + r) * 128 + rt * 16 + lr] = f2bf(acc[rt][r]);
}

// ---------------------------------------------------------------------------
// K3: per-(b,m) fused attention. 2048 WGs x 256 threads (4 waves).
// Wave w owns n in [w*128, w*128+128) for scores; r-cols [w*32,w*32+32) for arv;
// d-tile [w*16,w*16+16) for val.
// rv swizzle helper: byte ^= ((r&7)<<4) ^ ((r&24)<<2) -- alignment-safe (bits>=4).
// ---------------------------------------------------------------------------
__device__ __forceinline__ uint32_t rv_sw(int r, uint32_t nbyte) {
  return nbyte ^ ((uint32_t)(r & 7) << 4) ^ ((uint32_t)(r & 24) << 2);
}

__global__ __launch_bounds__(256, 4) void k_attn(
    const uint16_t* __restrict__ qh, const uint16_t* __restrict__ kh,
    const uint16_t* __restrict__ vhT, const uint16_t* __restrict__ qt,
    const float* __restrict__ rk, const float* __restrict__ rv,
    const uint16_t* __restrict__ WrvT, const float* __restrict__ brv,
    uint16_t* __restrict__ VAL) {
  // XCD swizzle: each XCD gets a contiguous bm range (one batch's kh/vhT in its L2)
  int bm = (blockIdx.x & 7) * 256 + (blockIdx.x >> 3);
  int b = bm >> 9;
  int t = threadIdx.x, lane = t & 63, w = t >> 6, lr = lane & 15, lg = lane >> 4;
  __shared__ alignas(16) uint16_t qh_lds[16 * 64];
  __shared__ alignas(16) uint16_t att_lds[16 * 512];  // swizzled rows of 1KB
  __shared__ alignas(16) uint16_t arv_lds[16 * 128];  // swizzled rows of 256B
  __shared__ alignas(16) uint16_t rvT[128 * 64];      // transposed rv chunk, swizzled
  __shared__ float red[2][16][4];
  const s16x8 z8 = {0, 0, 0, 0, 0, 0, 0, 0};

  for (int i = t; i < 1024; i += 256) qh_lds[i] = qh[(size_t)bm * 1024 + i];

  s16x8 aqt[4];
#pragma unroll
  for (int kk = 0; kk < 4; ++kk)
    aqt[kk] = *(const s16x8*)(qt + ((size_t)bm * 16 + lr) * 128 + kk * 32 + lg * 8);

  f32x4 acc[8];
#pragma unroll
  for (int j = 0; j < 8; ++j) acc[j] = (f32x4){0.f, 0.f, 0.f, 0.f};
  __syncthreads();

  int wn = w * 128;
  // ---- phase 1: score_2 = qt . r_k  (fp32 stream, cvt to bf16, direct B-frags)
  const float* rkb = rk + (size_t)bm * 65536;
#pragma unroll 4
  for (int j = 0; j < 8; ++j) {
    const float* rowp = rkb + (size_t)(wn + j * 16 + lr) * 128 + lg * 8;
#pragma unroll
    for (int kk = 0; kk < 4; ++kk) {
      float4 v0 = *(const float4*)(rowp + kk * 32);
      float4 v1 = *(const float4*)(rowp + kk * 32 + 4);
      acc[j] = MFMA16(aqt[kk], pack8(v0, v1), acc[j]);
    }
  }
  // ---- phase 2: score_1 via block-diagonal sparse-A MFMA over kh (scale baked in kh)
  const uint16_t* khb = kh + (size_t)b * 512 * 1024;
  for (int kk = 0; kk < 32; ++kk) {
    s16x8 a = *(const s16x8*)(qh_lds + (kk >> 1) * 64 + (kk & 1) * 32 + lg * 8);
    s16x8 az = (lr == (kk >> 1)) ? a : z8;
#pragma unroll
    for (int j = 0; j < 8; ++j) {
      s16x8 bf = *(const s16x8*)(khb + (size_t)(wn + j * 16 + lr) * 1024 + kk * 32 + lg * 8);
      acc[j] = MFMA16(az, bf, acc[j]);
    }
  }
  // ---- phase 3: softmax (rows h = lg*4+r, cols n)
  float mrow[4], inv[4];
#pragma unroll
  for (int r = 0; r < 4; ++r) {
    float mx = acc[0][r];
#pragma unroll
    for (int j = 1; j < 8; ++j) mx = fmaxf(mx, acc[j][r]);
#pragma unroll
    for (int off = 1; off < 16; off <<= 1) mx = fmaxf(mx, __shfl_xor(mx, off, 64));
    mrow[r] = mx;
  }
  if (lr == 0) {
#pragma unroll
    for (int r = 0; r < 4; ++r) red[0][lg * 4 + r][w] = mrow[r];
  }
  __syncthreads();
#pragma unroll
  for (int r = 0; r < 4; ++r) {
    const float* p = red[0][lg * 4 + r];
    mrow[r] = fmaxf(fmaxf(p[0], p[1]), fmaxf(p[2], p[3]));
  }
#pragma unroll
  for (int r = 0; r < 4; ++r) {
    float s = 0.f;
#pragma unroll
    for (int j = 0; j < 8; ++j) {
      float pj = __expf(acc[j][r] - mrow[r]);
      acc[j][r] = pj;
      s += pj;
    }
#pragma unroll
    for (int off = 1; off < 16; off <<= 1) s += __shfl_xor(s, off, 64);
    inv[r] = s;
  }
  if (lr == 0) {
#pragma unroll
    for (int r = 0; r < 4; ++r) red[1][lg * 4 + r][w] = inv[r];
  }
  __syncthreads();
#pragma unroll
  for (int r = 0; r < 4; ++r) {
    const float* p = red[1][lg * 4 + r];
    inv[r] = 1.f / (p[0] + p[1] + p[2] + p[3]);
  }
#pragma unroll
  for (int r = 0; r < 4; ++r) {
    int h = lg * 4 + r;
#pragma unroll
    for (int j = 0; j < 8; ++j) {
      int n = wn + j * 16 + lr;
      uint32_t off = (uint32_t)h * 1024 + (((uint32_t)n * 2) ^ ((uint32_t)(h & 7) << 4));
      *(uint16_t*)((char*)att_lds + off) = f2bf(acc[j][r] * inv[r]);
    }
  }
  __syncthreads();

  // ---- rv staging prefetch for chunk 0 (hides under phase 4b)
  int sn0 = (t >> 4) * 4;        // chunk-local n base, {0..60}
  int sc0 = (t & 15) * 8;        // r base, {0..120}
  const float* rvb = rv + (size_t)bm * 65536;
  float4 vreg[4][2];
  {
    const float* p = rvb + (size_t)sn0 * 128 + sc0;
#pragma unroll
    for (int j = 0; j < 4; ++j) {
      vreg[j][0] = *(const float4*)(p + j * 128);
      vreg[j][1] = *(const float4*)(p + j * 128 + 4);
    }
  }

  // ---- phase 4b: val1 via block-diagonal sparse-A MFMA over vhT (wave owns d-tile)
  f32x4 vacc0 = (f32x4){0.f, 0.f, 0.f, 0.f};
  f32x4 vacc1 = (f32x4){0.f, 0.f, 0.f, 0.f};
  const uint16_t* vtb = vhT + (size_t)b * 1024 * 512;
  for (int nk = 0; nk < 16; ++nk) {
    int nb = nk * 32 + lg * 8;
    s16x8 a = *(const s16x8*)((const char*)att_lds + lr * 1024 +
                              (((uint32_t)nb * 2) ^ ((uint32_t)(lr & 7) << 4)));
#pragma unroll
    for (int hp = 0; hp < 16; ++hp) {
      s16x8 az = (lr == hp) ? a : z8;
      s16x8 bf = *(const s16x8*)(vtb + (size_t)(hp * 64 + w * 16 + lr) * 512 + nb);
      if (hp & 1) vacc1 = MFMA16(az, bf, vacc1);
      else        vacc0 = MFMA16(az, bf, vacc0);
    }
  }

  // ---- phase 4a: arv[h,rc] = sum_n att[h,n] * r_v[m,n,rc], LDS-transposed chunks
  f32x4 arv0 = (f32x4){0.f, 0.f, 0.f, 0.f}, arv1 = arv0;
  for (int ch = 0; ch < 8; ++ch) {
    __syncthreads();  // prev chunk's reads done; rvT free
    // write transposed bf16 chunk (held in vreg) into rvT
#pragma unroll
    for (int cc = 0; cc < 8; ++cc) {
      int r = sc0 + cc;
      ushort4 u;
      u.x = f2bf(vreg[0][cc >> 2][cc & 3]);
      u.y = f2bf(vreg[1][cc >> 2][cc & 3]);
      u.z = f2bf(vreg[2][cc >> 2][cc & 3]);
      u.w = f2bf(vreg[3][cc >> 2][cc & 3]);
      *(ushort4*)((char*)rvT + r * 128 + rv_sw(r, (uint32_t)sn0 * 2)) = u;
    }
    __syncthreads();
    if (ch < 7) {  // async-stage next chunk
      const float* p = rvb + (size_t)((ch + 1) * 64 + sn0) * 128 + sc0;
#pragma unroll
      for (int j = 0; j < 4; ++j) {
        vreg[j][0] = *(const float4*)(p + j * 128);
        vreg[j][1] = *(const float4*)(p + j * 128 + 4);
      }
    }
#pragma unroll
    for (int kkl = 0; kkl < 2; ++kkl) {
      int kk = ch * 2 + kkl;
      int nb = kk * 32 + lg * 8;
      s16x8 a = *(const s16x8*)((const char*)att_lds + lr * 1024 +
                                (((uint32_t)nb * 2) ^ ((uint32_t)(lr & 7) << 4)));
      int nl2 = (kkl * 32 + lg * 8) * 2;
#pragma unroll
      for (int rt = 0; rt < 2; ++rt) {
        int rc = w * 32 + rt * 16 + lr;
        s16x8 bfr = *(const s16x8*)((const char*)rvT + rc * 128 + rv_sw(rc, (uint32_t)nl2));
        if (rt == 0) arv0 = MFMA16(a, bfr, arv0);
        else         arv1 = MFMA16(a, bfr, arv1);
      }
    }
  }

  f32x4 vacc;
#pragma unroll
  for (int r = 0; r < 4; ++r) vacc[r] = vacc0[r] + vacc1[r];

  // ---- phase 5: arv -> LDS (bf16, swizzled)
#pragma unroll
  for (int r = 0; r < 4; ++r) {
    int h = lg * 4 + r;
    uint32_t rc0 = (uint32_t)(w * 32 + lr) * 2;
    uint32_t rc1 = (uint32_t)(w * 32 + 16 + lr) * 2;
    *(uint16_t*)((char*)arv_lds + h * 256 + (rc0 ^ ((uint32_t)(h & 7) << 4))) = f2bf(arv0[r]);
    *(uint16_t*)((char*)arv_lds + h * 256 + (rc1 ^ ((uint32_t)(h & 7) << 4))) = f2bf(arv1[r]);
  }
  __syncthreads();
  // ---- phase 6: val2 = arv @ Wrv (+brv), accumulated into vacc
#pragma unroll
  for (int kk = 0; kk < 4; ++kk) {
    uint32_t rb = (uint32_t)(kk * 32 + lg * 8) * 2;
    s16x8 a = *(const s16x8*)((const char*)arv_lds + lr * 256 +
                              (rb ^ ((uint32_t)(lr & 7) << 4)));
    s16x8 bf = *(const s16x8*)(WrvT + (size_t)(w * 16 + lr) * 128 + kk * 32 + lg * 8);
    vacc = MFMA16(a, bf, vacc);
  }
  float bias = brv[w * 16 + lr];
#pragma unroll
  for (int r = 0; r < 4; ++r)
    VAL[(size_t)bm * 1024 + (lg * 4 + r) * 64 + w * 16 + lr] = f2bf(vacc[r] + bias);
}

// ---------------------------------------------------------------------------
// K5: out = VAL @ Wo + bo (fp32 out). Same structure as k_projqkv, bf16 A.
// ---------------------------------------------------------------------------
__global__ __launch_bounds__(256) void k_out(
    const uint16_t* __restrict__ A, const uint16_t* __restrict__ WT,
    const float* __restrict__ bias, float* __restrict__ out) {
  __shared__ alignas(16) uint16_t As[128 * 64];
  __shared__ alignas(16) uint16_t Bs[128 * 64];
  int t = threadIdx.x, lane = t & 63, w = t >> 6, lr = lane & 15, lg = lane >> 4;
  int m0 = blockIdx.x * 128, n0 = blockIdx.y * 128;
  int wm = (w >> 1) * 64, wn = (w & 1) * 64;
  f32x4 acc[4][4];
#pragma unroll
  for (int i = 0; i < 4; ++i)
#pragma unroll
    for (int j = 0; j < 4; ++j) acc[i][j] = (f32x4){0.f, 0.f, 0.f, 0.f};
  int srow = t >> 1, sh = t & 1;
  for (int ko = 0; ko < 16; ++ko) {
    __syncthreads();
    {
      const uint16_t* asrc = A + (size_t)(m0 + srow) * 1024 + ko * 64 + sh * 32;
      const uint16_t* bsrc = WT + (size_t)(n0 + srow) * 1024 + ko * 64 + sh * 32;
#pragma unroll
      for (int c = 0; c < 4; ++c) {
        s16x8 va = *(const s16x8*)(asrc + c * 8);
        *reinterpret_cast<s16x8*>((char*)As + srow * 128 +
                                  ((((sh * 4 + c) * 16)) ^ ((srow & 7) << 4))) = va;
        s16x8 vb = *(const s16x8*)(bsrc + c * 8);
        *reinterpret_cast<s16x8*>((char*)Bs + srow * 128 + (sh * 4 + c) * 16) = vb;
      }
    }
    __syncthreads();
#pragma unroll
    for (int kk = 0; kk < 2; ++kk) {
      s16x8 af[4], bf[4];
#pragma unroll
      for (int mt = 0; mt < 4; ++mt) {
        int row = wm + mt * 16 + lr;
        af[mt] = *(const s16x8*)((const char*)As + row * 128 +
                                 (((kk * 32 + lg * 8) * 2) ^ ((row & 7) << 4)));
      }
#pragma unroll
      for (int nt = 0; nt < 4; ++nt) {
        int row = wn + nt * 16 + lr;
        bf[nt] = *(const s16x8*)((const char*)Bs + row * 128 +
                                 (((kk * 32 + lg * 8) * 2) ^ ((row & 7) << 4)));
      }
#pragma unroll
      for (int mt = 0; mt < 4; ++mt)
#pragma unroll
        for (int nt = 0; nt < 4; ++nt)
          acc[mt][nt] = MFMA16(af[mt], bf[nt], acc[mt][nt]);
    }
  }
#pragma unroll
  for (int mt = 0; mt < 4; ++mt) {
#pragma unroll
    for (int nt = 0; nt < 4; ++nt) {
      int col = n0 + wn + nt * 16 + lr;
      float bcol = bias[col];
#pragma unroll
      for (int r = 0; r < 4; ++r) {
        int row = m0 + wm + mt * 16 + lg * 4 + r;
        out[(size_t)row * 1024 + col] = acc[mt][nt][r] + bcol;
      }
    }
  }
}

// ---------------------------------------------------------------------------
extern "C" void kernel_launch(void* const* d_in, const int* in_sizes, int n_in,
                              void* d_out, int out_size, void* d_ws, size_t ws_size,
                              hipStream_t stream) {
  const float* q   = (const float*)d_in[0];
  const float* k_  = (const float*)d_in[1];
  const float* v   = (const float*)d_in[2];
  const float* r_k = (const float*)d_in[3];
  const float* r_v = (const float*)d_in[4];
  const float* Wq  = (const float*)d_in[5];
  const float* bq  = (const float*)d_in[6];
  const float* Wk  = (const float*)d_in[7];
  const float* bk  = (const float*)d_in[8];
  const float* Wv  = (const float*)d_in[9];
  const float* bv  = (const float*)d_in[10];
  const float* Wrk = (const float*)d_in[11];
  // d_in[12] = brk: softmax-invariant, unused
  const float* Wrv = (const float*)d_in[13];
  const float* brv = (const float*)d_in[14];
  const float* Wo  = (const float*)d_in[15];
  const float* bo  = (const float*)d_in[16];
  (void)in_sizes; (void)n_in; (void)out_size;

  char* ws = (char*)d_ws;
  uint16_t* WqT  = (uint16_t*)(ws + (size_t)(0));
  uint16_t* WkT  = (uint16_t*)(ws + (size_t)(2u << 20));
  uint16_t* WvT  = (uint16_t*)(ws + (size_t)(4u << 20));
  uint16_t* WoT  = (uint16_t*)(ws + (size_t)(6u << 20));
  uint16_t* WrkB = (uint16_t*)(ws + (size_t)(8u << 20));
  uint16_t* WrvT = (uint16_t*)(ws + (size_t)(8u << 20) + (64u << 10));
  uint16_t* QH   = (uint16_t*)(ws + (size_t)(16u << 20));
  uint16_t* KH   = (uint16_t*)(ws + (size_t)(20u << 20));
  uint16_t* VHT  = (uint16_t*)(ws + (size_t)(24u << 20));
  uint16_t* QT   = (uint16_t*)(ws + (size_t)(28u << 20));
  uint16_t* VALB = (uint16_t*)(ws + (size_t)(36u << 20));
  if (ws_size < (size_t)(40u << 20)) return;  // need 40 MB of scratch

  dim3 blk(256, 1, 1);
  k_prep<<<dim3(256, 5, 1), blk, 0, stream>>>(Wq, Wk, Wv, Wo, Wrk, Wrv,
                                              WqT, WkT, WvT, WoT, WrkB, WrvT);
  k_projqkv<<<dim3(16, 8, 3), blk, 0, stream>>>(q, k_, v, WqT, bq, bk, bv, QH);
  k_qt<<<dim3(512, 1, 1), blk, 0, stream>>>(QH, WrkB, QT);
  k_attn<<<dim3(2048, 1, 1), blk, 0, stream>>>(QH, KH, VHT, QT, r_k, r_v,
                                               WrvT, brv, VALB);
  k_out<<<dim3(16, 8, 1), blk, 0, stream>>>(VALB, WoT, bo, (float*)d_out);
}

// Round 3
// 700.538 us; speedup vs baseline: 1.1245x; 1.0340x over previous
//
#include <hip/hip_runtime.h>
#include <hip/hip_bf16.h>
#include <stdint.h>

// RelationMultiHeadAttention on MI355X.
// Pipeline: k_prep (weightsT->bf16, pre-swizzled) -> k_projqkv (qh, kh*scale, vhT)
//           -> k_qt (qt = qh @ Wrk^T) -> k_attn (per (b,m): s2+s1+softmax+val1+arv+val2)
//           -> k_out (out = VAL @ Wo^T + bo, fp32)
// brk dropped (softmax-invariant); brv added via att-sums-to-1 identity.
// R3: explicit double-buffered register staging in k_attn phases 1/2/4b to get
// memory-level parallelism (R2 compiled to 52 VGPRs => serialized loads).

typedef __attribute__((ext_vector_type(4))) float f32x4;
typedef __attribute__((ext_vector_type(8))) short s16x8;

#define MFMA16(A, B, C) __builtin_amdgcn_mfma_f32_16x16x32_bf16(A, B, C, 0, 0, 0)

__device__ __forceinline__ uint16_t f2bf(float x) {
  uint32_t u = __float_as_uint(x);
  u += 0x7fffu + ((u >> 16) & 1u);   // RNE; inputs are finite
  return (uint16_t)(u >> 16);
}

__device__ __forceinline__ s16x8 pack8(float4 a, float4 b) {
  s16x8 r;
  r[0] = (short)f2bf(a.x); r[1] = (short)f2bf(a.y); r[2] = (short)f2bf(a.z); r[3] = (short)f2bf(a.w);
  r[4] = (short)f2bf(b.x); r[5] = (short)f2bf(b.y); r[6] = (short)f2bf(b.z); r[7] = (short)f2bf(b.w);
  return r;
}

// ---------------------------------------------------------------------------
// K0: weight prep. z=0..3: W[1024,1024] -> WT_sw bf16 [n][k] with per-row
// 16B-chunk XOR swizzle (chunk ^= n&7) so GEMM LDS staging is a linear copy
// and ds_read_b128 fragments are bank-conflict-light.
// z=4 (block 0 only): WrkB bf16 cast, WrvT bf16 transpose.
// ---------------------------------------------------------------------------
__global__ __launch_bounds__(256) void k_prep(
    const float* __restrict__ Wq, const float* __restrict__ Wk,
    const float* __restrict__ Wv, const float* __restrict__ Wo,
    const float* __restrict__ Wrk, const float* __restrict__ Wrv,
    uint16_t* __restrict__ WqT, uint16_t* __restrict__ WkT,
    uint16_t* __restrict__ WvT, uint16_t* __restrict__ WoT,
    uint16_t* __restrict__ WrkB, uint16_t* __restrict__ WrvT) {
  int z = blockIdx.y;
  int t = threadIdx.x;
  if (z == 4) {
    if (blockIdx.x == 0) {
      for (int i = t; i < 128 * 64; i += 256) WrkB[i] = f2bf(Wrk[i]);
      for (int i = t; i < 64 * 128; i += 256) {
        int d = i >> 7, r = i & 127;
        WrvT[i] = f2bf(Wrv[r * 64 + d]);
      }
    }
    return;
  }
  const float* W = (z == 0) ? Wq : (z == 1) ? Wk : (z == 2) ? Wv : Wo;
  uint16_t* O = (z == 0) ? WqT : (z == 1) ? WkT : (z == 2) ? WvT : WoT;
  int tk = (blockIdx.x >> 4) * 64;
  int tn = (blockIdx.x & 15) * 64;
  __shared__ float tile[64][65];
  {
    int kk = t >> 2, c0 = (t & 3) * 16;
    const float* src = W + (size_t)(tk + kk) * 1024 + tn + c0;
#pragma unroll
    for (int i = 0; i < 16; i += 4) {
      float4 v = *(const float4*)(src + i);
      tile[kk][c0 + i + 0] = v.x; tile[kk][c0 + i + 1] = v.y;
      tile[kk][c0 + i + 2] = v.z; tile[kk][c0 + i + 3] = v.w;
    }
  }
  __syncthreads();
  {
    int n_loc = t >> 2;
    int n = tn + n_loc;
#pragma unroll
    for (int cc = 0; cc < 2; ++cc) {
      int c = (t & 3) * 2 + cc;       // local chunk 0..7 in this k-window
      int csrc = c ^ (n & 7);         // swizzle source chunk
      s16x8 pk;
#pragma unroll
      for (int j = 0; j < 8; ++j) pk[j] = (short)f2bf(tile[csrc * 8 + j][n_loc]);
      *reinterpret_cast<s16x8*>(O + (size_t)n * 1024 + tk + c * 8) = pk;
    }
  }
}

// ---------------------------------------------------------------------------
// K1: Y = X@W + b for q,k,v in one launch (blockIdx.z = mode).
// mode 0: qh bf16 [2048,1024]
// mode 1: kh bf16 [2048,1024] scaled by 1/8 (score_1 scale baked in)
// mode 2: vhT bf16 [B,H,64,512] (n-contiguous, for val1 B-fragments)
// BM=BN=128, BK=64, 4 waves in 2x2 of 64x64 each.
// ---------------------------------------------------------------------------
__global__ __launch_bounds__(256) void k_projqkv(
    const float* __restrict__ Xq, const float* __restrict__ Xk,
    const float* __restrict__ Xv, const uint16_t* __restrict__ WTbase,
    const float* __restrict__ bq, const float* __restrict__ bk,
    const float* __restrict__ bv, uint16_t* __restrict__ outbase) {
  int mode = blockIdx.z;
  const float* X = (mode == 0) ? Xq : (mode == 1) ? Xk : Xv;
  const float* bias = (mode == 0) ? bq : (mode == 1) ? bk : bv;
  const uint16_t* WT = WTbase + (size_t)mode * (1u << 20);
  uint16_t* out = outbase + (size_t)mode * (2u << 20);

  __shared__ alignas(16) uint16_t As[128 * 64];
  __shared__ alignas(16) uint16_t Bs[128 * 64];
  int t = threadIdx.x, lane = t & 63, w = t >> 6, lr = lane & 15, lg = lane >> 4;
  int m0 = blockIdx.x * 128, n0 = blockIdx.y * 128;
  int wm = (w >> 1) * 64, wn = (w & 1) * 64;
  f32x4 acc[4][4];
#pragma unroll
  for (int i = 0; i < 4; ++i)
#pragma unroll
    for (int j = 0; j < 4; ++j) acc[i][j] = (f32x4){0.f, 0.f, 0.f, 0.f};
  int srow = t >> 1, sh = t & 1;
  for (int ko = 0; ko < 16; ++ko) {
    __syncthreads();
    {
      const float* src = X + (size_t)(m0 + srow) * 1024 + ko * 64 + sh * 32;
#pragma unroll
      for (int c = 0; c < 4; ++c) {
        float4 v0 = *(const float4*)(src + c * 8);
        float4 v1 = *(const float4*)(src + c * 8 + 4);
        s16x8 pk = pack8(v0, v1);
        *reinterpret_cast<s16x8*>((char*)As + srow * 128 +
                                  ((((sh * 4 + c) * 16)) ^ ((srow & 7) << 4))) = pk;
      }
      const uint16_t* bsrc = WT + (size_t)(n0 + srow) * 1024 + ko * 64 + sh * 32;
#pragma unroll
      for (int c = 0; c < 4; ++c) {
        s16x8 vb = *(const s16x8*)(bsrc + c * 8);
        *reinterpret_cast<s16x8*>((char*)Bs + srow * 128 + (sh * 4 + c) * 16) = vb;
      }
    }
    __syncthreads();
#pragma unroll
    for (int kk = 0; kk < 2; ++kk) {
      s16x8 af[4], bf[4];
#pragma unroll
      for (int mt = 0; mt < 4; ++mt) {
        int row = wm + mt * 16 + lr;
        af[mt] = *(const s16x8*)((const char*)As + row * 128 +
                                 (((kk * 32 + lg * 8) * 2) ^ ((row & 7) << 4)));
      }
#pragma unroll
      for (int nt = 0; nt < 4; ++nt) {
        int row = wn + nt * 16 + lr;
        bf[nt] = *(const s16x8*)((const char*)Bs + row * 128 +
                                 (((kk * 32 + lg * 8) * 2) ^ ((row & 7) << 4)));
      }
#pragma unroll
      for (int mt = 0; mt < 4; ++mt)
#pragma unroll
        for (int nt = 0; nt < 4; ++nt)
          acc[mt][nt] = MFMA16(af[mt], bf[nt], acc[mt][nt]);
    }
  }
  float sc = (mode == 1) ? 0.125f : 1.0f;
#pragma unroll
  for (int mt = 0; mt < 4; ++mt) {
#pragma unroll
    for (int nt = 0; nt < 4; ++nt) {
      int col = n0 + wn + nt * 16 + lr;
      float bcol = bias[col];
      if (mode != 2) {
#pragma unroll
        for (int r = 0; r < 4; ++r) {
          int row = m0 + wm + mt * 16 + lg * 4 + r;
          out[(size_t)row * 1024 + col] = f2bf((acc[mt][nt][r] + bcol) * sc);
        }
      } else {
        int row0 = m0 + wm + mt * 16 + lg * 4;  // sequence position base
        int b = row0 >> 9, n = row0 & 511;
        int h = col >> 6, d = col & 63;
        ushort4 pk;
        pk.x = f2bf(acc[mt][nt][0] + bcol);
        pk.y = f2bf(acc[mt][nt][1] + bcol);
        pk.z = f2bf(acc[mt][nt][2] + bcol);
        pk.w = f2bf(acc[mt][nt][3] + bcol);
        *reinterpret_cast<ushort4*>(out + ((size_t)(b * 16 + h) * 64 + d) * 512 + n) = pk;
      }
    }
  }
}

// ---------------------------------------------------------------------------
// K1b: qt[32768,128] = qh (viewed [32768,64]) @ WrkB^T. K=64, direct-global frags.
// row = bm*16 + h; output layout = [B,M,H,DR] (contiguous per (b,m)).
// ---------------------------------------------------------------------------
__global__ __launch_bounds__(256) void k_qt(
    const uint16_t* __restrict__ qh, const uint16_t* __restrict__ WrkB,
    uint16_t* __restrict__ qt) {
  int t = threadIdx.x, lane = t & 63, w = t >> 6, lr = lane & 15, lg = lane >> 4;
  int row0 = blockIdx.x * 64 + w * 16;
  f32x4 acc[8];
#pragma unroll
  for (int i = 0; i < 8; ++i) acc[i] = (f32x4){0.f, 0.f, 0.f, 0.f};
  s16x8 af[2];
#pragma unroll
  for (int kk = 0; kk < 2; ++kk)
    af[kk] = *(const s16x8*)(qh + (size_t)(row0 + lr) * 64 + kk * 32 + lg * 8);
#pragma unroll
  for (int rt = 0; rt < 8; ++rt) {
#pragma unroll
    for (int kk = 0; kk < 2; ++kk) {
      s16x8 bf = *(const s16x8*)(WrkB + (size_t)(rt * 16 + lr) * 64 + kk * 32 + lg * 8);
      acc[rt] = MFMA16(af[kk], bf, acc[rt]);
    }
  }
#pragma unroll
  for (int rt = 0; rt < 8; ++rt)
#pragma unroll
    for (int r = 0; r < 4; ++r)
      qt[(size_t)(row0 + lg * 4 + r) * 128 + rt * 16 + lr] = f2bf(acc[rt][r]);
}

// ---------------------------------------------------------------------------
// K3: per-(b,m) fused attention. 2048 WGs x 256 threads (4 waves).
// Wave w owns n in [w*128, w*128+128) for scores; r-cols [w*32,w*32+32) for arv;
// d-tile [w*16,w*16+16) for val.
// rv swizzle helper: byte ^= ((r&7)<<4) ^ ((r&24)<<2) -- alignment-safe (bits>=4).
// ---------------------------------------------------------------------------
__device__ __forceinline__ uint32_t rv_sw(int r, uint32_t nbyte) {
  return nbyte ^ ((uint32_t)(r & 7) << 4) ^ ((uint32_t)(r & 24) << 2);
}

__global__ __launch_bounds__(256, 3) void k_attn(
    const uint16_t* __restrict__ qh, const uint16_t* __restrict__ kh,
    const uint16_t* __restrict__ vhT, const uint16_t* __restrict__ qt,
    const float* __restrict__ rk, const float* __restrict__ rv,
    const uint16_t* __restrict__ WrvT, const float* __restrict__ brv,
    uint16_t* __restrict__ VAL) {
  // XCD swizzle: each XCD gets a contiguous bm range (one batch's kh/vhT in its L2)
  int bm = (blockIdx.x & 7) * 256 + (blockIdx.x >> 3);
  int b = bm >> 9;
  int t = threadIdx.x, lane = t & 63, w = t >> 6, lr = lane & 15, lg = lane >> 4;
  __shared__ alignas(16) uint16_t qh_lds[16 * 64];
  __shared__ alignas(16) uint16_t att_lds[16 * 512];  // swizzled rows of 1KB
  __shared__ alignas(16) uint16_t arv_lds[16 * 128];  // swizzled rows of 256B
  __shared__ alignas(16) uint16_t rvT[128 * 64];      // transposed rv chunk, swizzled
  __shared__ float red[2][16][4];
  const s16x8 z8 = {0, 0, 0, 0, 0, 0, 0, 0};

  for (int i = t; i < 1024; i += 256) qh_lds[i] = qh[(size_t)bm * 1024 + i];

  s16x8 aqt[4];
#pragma unroll
  for (int kk = 0; kk < 4; ++kk)
    aqt[kk] = *(const s16x8*)(qt + ((size_t)bm * 16 + lr) * 128 + kk * 32 + lg * 8);

  f32x4 acc[8];
#pragma unroll
  for (int j = 0; j < 8; ++j) acc[j] = (f32x4){0.f, 0.f, 0.f, 0.f};
  __syncthreads();

  int wn = w * 128;
  // ---- phase 1: score_2 = qt . r_k  (fp32 HBM stream, double-buffered regs)
  const float* rkrow = rk + (size_t)bm * 65536 + (size_t)(wn + lr) * 128 + lg * 8;
  float4 rA[8], rB[8];
#define LDR(buf, jj) { _Pragma("unroll") for (int c = 0; c < 4; ++c) { \
    buf[c * 2]     = *(const float4*)(rkrow + (size_t)(jj) * 2048 + c * 32); \
    buf[c * 2 + 1] = *(const float4*)(rkrow + (size_t)(jj) * 2048 + c * 32 + 4); } }
  LDR(rA, 0)
#pragma unroll
  for (int j = 0; j < 8; j += 2) {
    LDR(rB, j + 1)
#pragma unroll
    for (int kk = 0; kk < 4; ++kk)
      acc[j] = MFMA16(aqt[kk], pack8(rA[kk * 2], rA[kk * 2 + 1]), acc[j]);
    if (j + 2 < 8) { LDR(rA, j + 2) }
#pragma unroll
    for (int kk = 0; kk < 4; ++kk)
      acc[j + 1] = MFMA16(aqt[kk], pack8(rB[kk * 2], rB[kk * 2 + 1]), acc[j + 1]);
  }
#undef LDR

  // ---- phase 2: score_1 via block-diagonal sparse-A MFMA over kh (scale in kh)
  //      kk-rotated double-buffered fragment arrays (8 L2 loads in flight).
  const uint16_t* khrow = kh + (size_t)b * 512 * 1024 + (size_t)(wn + lr) * 1024 + lg * 8;
  {
    s16x8 kA[8], kB[8];
#define LDKH(buf, kkv) { _Pragma("unroll") for (int j = 0; j < 8; ++j) \
    buf[j] = *(const s16x8*)(khrow + (size_t)(j) * 16384 + (kkv) * 32); }
    LDKH(kA, 0)
#pragma unroll 1
    for (int kk = 0; kk < 32; kk += 2) {
      LDKH(kB, kk + 1)
      {
        s16x8 a = *(const s16x8*)(qh_lds + (kk >> 1) * 64 + (kk & 1) * 32 + lg * 8);
        s16x8 az = (lr == (kk >> 1)) ? a : z8;
#pragma unroll
        for (int j = 0; j < 8; ++j) acc[j] = MFMA16(az, kA[j], acc[j]);
      }
      if (kk + 2 < 32) { LDKH(kA, kk + 2) }
      {
        s16x8 a = *(const s16x8*)(qh_lds + (kk >> 1) * 64 + 32 + lg * 8);
        s16x8 az = (lr == (kk >> 1)) ? a : z8;
#pragma unroll
        for (int j = 0; j < 8; ++j) acc[j] = MFMA16(az, kB[j], acc[j]);
      }
    }
#undef LDKH
  }

  // ---- phase 3: softmax (rows h = lg*4+r, cols n)
  float mrow[4], inv[4];
#pragma unroll
  for (int r = 0; r < 4; ++r) {
    float mx = acc[0][r];
#pragma unroll
    for (int j = 1; j < 8; ++j) mx = fmaxf(mx, acc[j][r]);
#pragma unroll
    for (int off = 1; off < 16; off <<= 1) mx = fmaxf(mx, __shfl_xor(mx, off, 64));
    mrow[r] = mx;
  }
  if (lr == 0) {
#pragma unroll
    for (int r = 0; r < 4; ++r) red[0][lg * 4 + r][w] = mrow[r];
  }
  __syncthreads();
#pragma unroll
  for (int r = 0; r < 4; ++r) {
    const float* p = red[0][lg * 4 + r];
    mrow[r] = fmaxf(fmaxf(p[0], p[1]), fmaxf(p[2], p[3]));
  }
#pragma unroll
  for (int r = 0; r < 4; ++r) {
    float s = 0.f;
#pragma unroll
    for (int j = 0; j < 8; ++j) {
      float pj = __expf(acc[j][r] - mrow[r]);
      acc[j][r] = pj;
      s += pj;
    }
#pragma unroll
    for (int off = 1; off < 16; off <<= 1) s += __shfl_xor(s, off, 64);
    inv[r] = s;
  }
  if (lr == 0) {
#pragma unroll
    for (int r = 0; r < 4; ++r) red[1][lg * 4 + r][w] = inv[r];
  }
  __syncthreads();
#pragma unroll
  for (int r = 0; r < 4; ++r) {
    const float* p = red[1][lg * 4 + r];
    inv[r] = 1.f / (p[0] + p[1] + p[2] + p[3]);
  }
#pragma unroll
  for (int r = 0; r < 4; ++r) {
    int h = lg * 4 + r;
#pragma unroll
    for (int j = 0; j < 8; ++j) {
      int n = wn + j * 16 + lr;
      uint32_t off = (uint32_t)h * 1024 + (((uint32_t)n * 2) ^ ((uint32_t)(h & 7) << 4));
      *(uint16_t*)((char*)att_lds + off) = f2bf(acc[j][r] * inv[r]);
    }
  }
  __syncthreads();

  // ---- rv staging prefetch for chunk 0 (in flight under all of phase 4b)
  int sn0 = (t >> 4) * 4;        // chunk-local n base, {0..60}
  int sc0 = (t & 15) * 8;        // r base, {0..120}
  const float* rvb = rv + (size_t)bm * 65536;
  float4 vreg[4][2];
  {
    const float* p = rvb + (size_t)sn0 * 128 + sc0;
#pragma unroll
    for (int j = 0; j < 4; ++j) {
      vreg[j][0] = *(const float4*)(p + j * 128);
      vreg[j][1] = *(const float4*)(p + j * 128 + 4);
    }
  }

  // ---- phase 4b: val1 via block-diagonal sparse-A MFMA over vhT, hp half-group
  //      double-buffered fragment arrays (8 L2 loads in flight).
  f32x4 vacc0 = (f32x4){0.f, 0.f, 0.f, 0.f};
  f32x4 vacc1 = (f32x4){0.f, 0.f, 0.f, 0.f};
  const uint16_t* vtrow = vhT + (size_t)b * 1024 * 512 + (size_t)(w * 16 + lr) * 512 + lg * 8;
  {
    s16x8 vA[8], vB[8];
#define LDVT(buf, hp0, nkv) { _Pragma("unroll") for (int i = 0; i < 8; ++i) \
    buf[i] = *(const s16x8*)(vtrow + (size_t)((hp0) + i) * 32768 + (nkv) * 32); }
    LDVT(vA, 0, 0)
#pragma unroll 1
    for (int nk = 0; nk < 16; ++nk) {
      int nb = nk * 32 + lg * 8;
      s16x8 a = *(const s16x8*)((const char*)att_lds + lr * 1024 +
                                (((uint32_t)nb * 2) ^ ((uint32_t)(lr & 7) << 4)));
      LDVT(vB, 8, nk)
#pragma unroll
      for (int hp = 0; hp < 8; ++hp) {
        s16x8 az = (lr == hp) ? a : z8;
        if (hp & 1) vacc1 = MFMA16(az, vA[hp], vacc1);
        else        vacc0 = MFMA16(az, vA[hp], vacc0);
      }
      if (nk < 15) { LDVT(vA, 0, nk + 1) }
#pragma unroll
      for (int hp = 8; hp < 16; ++hp) {
        s16x8 az = (lr == hp) ? a : z8;
        if (hp & 1) vacc1 = MFMA16(az, vB[hp - 8], vacc1);
        else        vacc0 = MFMA16(az, vB[hp - 8], vacc0);
      }
    }
#undef LDVT
  }

  // ---- phase 4a: arv[h,rc] = sum_n att[h,n] * r_v[m,n,rc], LDS-transposed chunks
  f32x4 arv0 = (f32x4){0.f, 0.f, 0.f, 0.f}, arv1 = arv0;
  for (int ch = 0; ch < 8; ++ch) {
    __syncthreads();  // prev chunk's reads done; rvT free
    // write transposed bf16 chunk (held in vreg) into rvT
#pragma unroll
    for (int cc = 0; cc < 8; ++cc) {
      int r = sc0 + cc;
      ushort4 u;
      u.x = f2bf(vreg[0][cc >> 2][cc & 3]);
      u.y = f2bf(vreg[1][cc >> 2][cc & 3]);
      u.z = f2bf(vreg[2][cc >> 2][cc & 3]);
      u.w = f2bf(vreg[3][cc >> 2][cc & 3]);
      *(ushort4*)((char*)rvT + r * 128 + rv_sw(r, (uint32_t)sn0 * 2)) = u;
    }
    __syncthreads();
    if (ch < 7) {  // async-stage next chunk
      const float* p = rvb + (size_t)((ch + 1) * 64 + sn0) * 128 + sc0;
#pragma unroll
      for (int j = 0; j < 4; ++j) {
        vreg[j][0] = *(const float4*)(p + j * 128);
        vreg[j][1] = *(const float4*)(p + j * 128 + 4);
      }
    }
#pragma unroll
    for (int kkl = 0; kkl < 2; ++kkl) {
      int kk = ch * 2 + kkl;
      int nb = kk * 32 + lg * 8;
      s16x8 a = *(const s16x8*)((const char*)att_lds + lr * 1024 +
                                (((uint32_t)nb * 2) ^ ((uint32_t)(lr & 7) << 4)));
      int nl2 = (kkl * 32 + lg * 8) * 2;
#pragma unroll
      for (int rt = 0; rt < 2; ++rt) {
        int rc = w * 32 + rt * 16 + lr;
        s16x8 bfr = *(const s16x8*)((const char*)rvT + rc * 128 + rv_sw(rc, (uint32_t)nl2));
        if (rt == 0) arv0 = MFMA16(a, bfr, arv0);
        else         arv1 = MFMA16(a, bfr, arv1);
      }
    }
  }

  f32x4 vacc;
#pragma unroll
  for (int r = 0; r < 4; ++r) vacc[r] = vacc0[r] + vacc1[r];

  // ---- phase 5: arv -> LDS (bf16, swizzled)
#pragma unroll
  for (int r = 0; r < 4; ++r) {
    int h = lg * 4 + r;
    uint32_t rc0 = (uint32_t)(w * 32 + lr) * 2;
    uint32_t rc1 = (uint32_t)(w * 32 + 16 + lr) * 2;
    *(uint16_t*)((char*)arv_lds + h * 256 + (rc0 ^ ((uint32_t)(h & 7) << 4))) = f2bf(arv0[r]);
    *(uint16_t*)((char*)arv_lds + h * 256 + (rc1 ^ ((uint32_t)(h & 7) << 4))) = f2bf(arv1[r]);
  }
  __syncthreads();
  // ---- phase 6: val2 = arv @ Wrv (+brv), accumulated into vacc
#pragma unroll
  for (int kk = 0; kk < 4; ++kk) {
    uint32_t rb = (uint32_t)(kk * 32 + lg * 8) * 2;
    s16x8 a = *(const s16x8*)((const char*)arv_lds + lr * 256 +
                              (rb ^ ((uint32_t)(lr & 7) << 4)));
    s16x8 bf = *(const s16x8*)(WrvT + (size_t)(w * 16 + lr) * 128 + kk * 32 + lg * 8);
    vacc = MFMA16(a, bf, vacc);
  }
  float bias = brv[w * 16 + lr];
#pragma unroll
  for (int r = 0; r < 4; ++r)
    VAL[(size_t)bm * 1024 + (lg * 4 + r) * 64 + w * 16 + lr] = f2bf(vacc[r] + bias);
}

// ---------------------------------------------------------------------------
// K5: out = VAL @ Wo + bo (fp32 out). Same structure as k_projqkv, bf16 A.
// ---------------------------------------------------------------------------
__global__ __launch_bounds__(256) void k_out(
    const uint16_t* __restrict__ A, const uint16_t* __restrict__ WT,
    const float* __restrict__ bias, float* __restrict__ out) {
  __shared__ alignas(16) uint16_t As[128 * 64];
  __shared__ alignas(16) uint16_t Bs[128 * 64];
  int t = threadIdx.x, lane = t & 63, w = t >> 6, lr = lane & 15, lg = lane >> 4;
  int m0 = blockIdx.x * 128, n0 = blockIdx.y * 128;
  int wm = (w >> 1) * 64, wn = (w & 1) * 64;
  f32x4 acc[4][4];
#pragma unroll
  for (int i = 0; i < 4; ++i)
#pragma unroll
    for (int j = 0; j < 4; ++j) acc[i][j] = (f32x4){0.f, 0.f, 0.f, 0.f};
  int srow = t >> 1, sh = t & 1;
  for (int ko = 0; ko < 16; ++ko) {
    __syncthreads();
    {
      const uint16_t* asrc = A + (size_t)(m0 + srow) * 1024 + ko * 64 + sh * 32;
      const uint16_t* bsrc = WT + (size_t)(n0 + srow) * 1024 + ko * 64 + sh * 32;
#pragma unroll
      for (int c = 0; c < 4; ++c) {
        s16x8 va = *(const s16x8*)(asrc + c * 8);
        *reinterpret_cast<s16x8*>((char*)As + srow * 128 +
                                  ((((sh * 4 + c) * 16)) ^ ((srow & 7) << 4))) = va;
        s16x8 vb = *(const s16x8*)(bsrc + c * 8);
        *reinterpret_cast<s16x8*>((char*)Bs + srow * 128 + (sh * 4 + c) * 16) = vb;
      }
    }
    __syncthreads();
#pragma unroll
    for (int kk = 0; kk < 2; ++kk) {
      s16x8 af[4], bf[4];
#pragma unroll
      for (int mt = 0; mt < 4; ++mt) {
        int row = wm + mt * 16 + lr;
        af[mt] = *(const s16x8*)((const char*)As + row * 128 +
                                 (((kk * 32 + lg * 8) * 2) ^ ((row & 7) << 4)));
      }
#pragma unroll
      for (int nt = 0; nt < 4; ++nt) {
        int row = wn + nt * 16 + lr;
        bf[nt] = *(const s16x8*)((const char*)Bs + row * 128 +
                                 (((kk * 32 + lg * 8) * 2) ^ ((row & 7) << 4)));
      }
#pragma unroll
      for (int mt = 0; mt < 4; ++mt)
#pragma unroll
        for (int nt = 0; nt < 4; ++nt)
          acc[mt][nt] = MFMA16(af[mt], bf[nt], acc[mt][nt]);
    }
  }
#pragma unroll
  for (int mt = 0; mt < 4; ++mt) {
#pragma unroll
    for (int nt = 0; nt < 4; ++nt) {
      int col = n0 + wn + nt * 16 + lr;
      float bcol = bias[col];
#pragma unroll
      for (int r = 0; r < 4; ++r) {
        int row = m0 + wm + mt * 16 + lg * 4 + r;
        out[(size_t)row * 1024 + col] = acc[mt][nt][r] + bcol;
      }
    }
  }
}

// ---------------------------------------------------------------------------
extern "C" void kernel_launch(void* const* d_in, const int* in_sizes, int n_in,
                              void* d_out, int out_size, void* d_ws, size_t ws_size,
                              hipStream_t stream) {
  const float* q   = (const float*)d_in[0];
  const float* k_  = (const float*)d_in[1];
  const float* v   = (const float*)d_in[2];
  const float* r_k = (const float*)d_in[3];
  const float* r_v = (const float*)d_in[4];
  const float* Wq  = (const float*)d_in[5];
  const float* bq  = (const float*)d_in[6];
  const float* Wk  = (const float*)d_in[7];
  const float* bk  = (const float*)d_in[8];
  const float* Wv  = (const float*)d_in[9];
  const float* bv  = (const float*)d_in[10];
  const float* Wrk = (const float*)d_in[11];
  // d_in[12] = brk: softmax-invariant, unused
  const float* Wrv = (const float*)d_in[13];
  const float* brv = (const float*)d_in[14];
  const float* Wo  = (const float*)d_in[15];
  const float* bo  = (const float*)d_in[16];
  (void)in_sizes; (void)n_in; (void)out_size;

  char* ws = (char*)d_ws;
  uint16_t* WqT  = (uint16_t*)(ws + (size_t)(0));
  uint16_t* WkT  = (uint16_t*)(ws + (size_t)(2u << 20));
  uint16_t* WvT  = (uint16_t*)(ws + (size_t)(4u << 20));
  uint16_t* WoT  = (uint16_t*)(ws + (size_t)(6u << 20));
  uint16_t* WrkB = (uint16_t*)(ws + (size_t)(8u << 20));
  uint16_t* WrvT = (uint16_t*)(ws + (size_t)(8u << 20) + (64u << 10));
  uint16_t* QH   = (uint16_t*)(ws + (size_t)(16u << 20));
  uint16_t* KH   = (uint16_t*)(ws + (size_t)(20u << 20));
  uint16_t* VHT  = (uint16_t*)(ws + (size_t)(24u << 20));
  uint16_t* QT   = (uint16_t*)(ws + (size_t)(28u << 20));
  uint16_t* VALB = (uint16_t*)(ws + (size_t)(36u << 20));
  if (ws_size < (size_t)(40u << 20)) return;  // need 40 MB of scratch

  dim3 blk(256, 1, 1);
  k_prep<<<dim3(256, 5, 1), blk, 0, stream>>>(Wq, Wk, Wv, Wo, Wrk, Wrv,
                                              WqT, WkT, WvT, WoT, WrkB, WrvT);
  k_projqkv<<<dim3(16, 8, 3), blk, 0, stream>>>(q, k_, v, WqT, bq, bk, bv, QH);
  k_qt<<<dim3(512, 1, 1), blk, 0, stream>>>(QH, WrkB, QT);
  k_attn<<<dim3(2048, 1, 1), blk, 0, stream>>>(QH, KH, VHT, QT, r_k, r_v,
                                               WrvT, brv, VALB);
  k_out<<<dim3(16, 8, 1), blk, 0, stream>>>(VALB, WoT, bo, (float*)d_out);
}

// Round 4
// 558.405 us; speedup vs baseline: 1.4107x; 1.2545x over previous
//
#include <hip/hip_runtime.h>
#include <hip/hip_bf16.h>
#include <hip/hip_fp16.h>
#include <stdint.h>

// RelationMultiHeadAttention on MI355X.
// R4 pipeline:
//   k_prep -> k_projqkv (qh, kh/8, vhT) -> k_qt -> k_score1 (S1=qh.khT, fp16, swizzled-n)
//   -> k_s2v2 (per (b,m): gll-pipelined rk stream + S1-add + softmax + gll-pipelined
//              rv stream -> arv -> val2=arv@Wrv+brv -> V2; att -> global in-place)
//   -> k_val1 (val = att@vh + V2 -> VALB) -> k_out
// Fallback (ws < 74MB): R3 fused k_attn path.

typedef __attribute__((ext_vector_type(4))) float f32x4;
typedef __attribute__((ext_vector_type(8))) short s16x8;

#define MFMA16(A, B, C) __builtin_amdgcn_mfma_f32_16x16x32_bf16(A, B, C, 0, 0, 0)

__device__ __forceinline__ uint16_t f2bf(float x) {
  uint32_t u = __float_as_uint(x);
  u += 0x7fffu + ((u >> 16) & 1u);
  return (uint16_t)(u >> 16);
}
__device__ __forceinline__ float bf2f(uint16_t u) {
  return __uint_as_float((uint32_t)u << 16);
}
__device__ __forceinline__ uint16_t f2h(float x) {
  __half h = __float2half_rn(x);
  return *reinterpret_cast<uint16_t*>(&h);
}
__device__ __forceinline__ float h2f(uint16_t u) {
  __half h = *reinterpret_cast<__half*>(&u);
  return __half2float(h);
}

__device__ __forceinline__ s16x8 pack8(float4 a, float4 b) {
  s16x8 r;
  r[0] = (short)f2bf(a.x); r[1] = (short)f2bf(a.y); r[2] = (short)f2bf(a.z); r[3] = (short)f2bf(a.w);
  r[4] = (short)f2bf(b.x); r[5] = (short)f2bf(b.y); r[6] = (short)f2bf(b.z); r[7] = (short)f2bf(b.w);
  return r;
}

__device__ __forceinline__ void gll16(const void* g, void* l) {
  __builtin_amdgcn_global_load_lds(
      (const __attribute__((address_space(1))) uint32_t*)(g),
      (__attribute__((address_space(3))) uint32_t*)(l), 16, 0, 0);
}

// ---------------------------------------------------------------------------
// K0: weight prep (unchanged from R3).
// ---------------------------------------------------------------------------
__global__ __launch_bounds__(256) void k_prep(
    const float* __restrict__ Wq, const float* __restrict__ Wk,
    const float* __restrict__ Wv, const float* __restrict__ Wo,
    const float* __restrict__ Wrk, const float* __restrict__ Wrv,
    uint16_t* __restrict__ WqT, uint16_t* __restrict__ WkT,
    uint16_t* __restrict__ WvT, uint16_t* __restrict__ WoT,
    uint16_t* __restrict__ WrkB, uint16_t* __restrict__ WrvT) {
  int z = blockIdx.y;
  int t = threadIdx.x;
  if (z == 4) {
    if (blockIdx.x == 0) {
      for (int i = t; i < 128 * 64; i += 256) WrkB[i] = f2bf(Wrk[i]);
      for (int i = t; i < 64 * 128; i += 256) {
        int d = i >> 7, r = i & 127;
        WrvT[i] = f2bf(Wrv[r * 64 + d]);
      }
    }
    return;
  }
  const float* W = (z == 0) ? Wq : (z == 1) ? Wk : (z == 2) ? Wv : Wo;
  uint16_t* O = (z == 0) ? WqT : (z == 1) ? WkT : (z == 2) ? WvT : WoT;
  int tk = (blockIdx.x >> 4) * 64;
  int tn = (blockIdx.x & 15) * 64;
  __shared__ float tile[64][65];
  {
    int kk = t >> 2, c0 = (t & 3) * 16;
    const float* src = W + (size_t)(tk + kk) * 1024 + tn + c0;
#pragma unroll
    for (int i = 0; i < 16; i += 4) {
      float4 v = *(const float4*)(src + i);
      tile[kk][c0 + i + 0] = v.x; tile[kk][c0 + i + 1] = v.y;
      tile[kk][c0 + i + 2] = v.z; tile[kk][c0 + i + 3] = v.w;
    }
  }
  __syncthreads();
  {
    int n_loc = t >> 2;
    int n = tn + n_loc;
#pragma unroll
    for (int cc = 0; cc < 2; ++cc) {
      int c = (t & 3) * 2 + cc;
      int csrc = c ^ (n & 7);
      s16x8 pk;
#pragma unroll
      for (int j = 0; j < 8; ++j) pk[j] = (short)f2bf(tile[csrc * 8 + j][n_loc]);
      *reinterpret_cast<s16x8*>(O + (size_t)n * 1024 + tk + c * 8) = pk;
    }
  }
}

// ---------------------------------------------------------------------------
// K1: projections (unchanged from R3).
// ---------------------------------------------------------------------------
__global__ __launch_bounds__(256) void k_projqkv(
    const float* __restrict__ Xq, const float* __restrict__ Xk,
    const float* __restrict__ Xv, const uint16_t* __restrict__ WTbase,
    const float* __restrict__ bq, const float* __restrict__ bk,
    const float* __restrict__ bv, uint16_t* __restrict__ outbase) {
  int mode = blockIdx.z;
  const float* X = (mode == 0) ? Xq : (mode == 1) ? Xk : Xv;
  const float* bias = (mode == 0) ? bq : (mode == 1) ? bk : bv;
  const uint16_t* WT = WTbase + (size_t)mode * (1u << 20);
  uint16_t* out = outbase + (size_t)mode * (2u << 20);

  __shared__ alignas(16) uint16_t As[128 * 64];
  __shared__ alignas(16) uint16_t Bs[128 * 64];
  int t = threadIdx.x, lane = t & 63, w = t >> 6, lr = lane & 15, lg = lane >> 4;
  int m0 = blockIdx.x * 128, n0 = blockIdx.y * 128;
  int wm = (w >> 1) * 64, wn = (w & 1) * 64;
  f32x4 acc[4][4];
#pragma unroll
  for (int i = 0; i < 4; ++i)
#pragma unroll
    for (int j = 0; j < 4; ++j) acc[i][j] = (f32x4){0.f, 0.f, 0.f, 0.f};
  int srow = t >> 1, sh = t & 1;
  for (int ko = 0; ko < 16; ++ko) {
    __syncthreads();
    {
      const float* src = X + (size_t)(m0 + srow) * 1024 + ko * 64 + sh * 32;
#pragma unroll
      for (int c = 0; c < 4; ++c) {
        float4 v0 = *(const float4*)(src + c * 8);
        float4 v1 = *(const float4*)(src + c * 8 + 4);
        s16x8 pk = pack8(v0, v1);
        *reinterpret_cast<s16x8*>((char*)As + srow * 128 +
                                  ((((sh * 4 + c) * 16)) ^ ((srow & 7) << 4))) = pk;
      }
      const uint16_t* bsrc = WT + (size_t)(n0 + srow) * 1024 + ko * 64 + sh * 32;
#pragma unroll
      for (int c = 0; c < 4; ++c) {
        s16x8 vb = *(const s16x8*)(bsrc + c * 8);
        *reinterpret_cast<s16x8*>((char*)Bs + srow * 128 + (sh * 4 + c) * 16) = vb;
      }
    }
    __syncthreads();
#pragma unroll
    for (int kk = 0; kk < 2; ++kk) {
      s16x8 af[4], bf[4];
#pragma unroll
      for (int mt = 0; mt < 4; ++mt) {
        int row = wm + mt * 16 + lr;
        af[mt] = *(const s16x8*)((const char*)As + row * 128 +
                                 (((kk * 32 + lg * 8) * 2) ^ ((row & 7) << 4)));
      }
#pragma unroll
      for (int nt = 0; nt < 4; ++nt) {
        int row = wn + nt * 16 + lr;
        bf[nt] = *(const s16x8*)((const char*)Bs + row * 128 +
                                 (((kk * 32 + lg * 8) * 2) ^ ((row & 7) << 4)));
      }
#pragma unroll
      for (int mt = 0; mt < 4; ++mt)
#pragma unroll
        for (int nt = 0; nt < 4; ++nt)
          acc[mt][nt] = MFMA16(af[mt], bf[nt], acc[mt][nt]);
    }
  }
  float sc = (mode == 1) ? 0.125f : 1.0f;
#pragma unroll
  for (int mt = 0; mt < 4; ++mt) {
#pragma unroll
    for (int nt = 0; nt < 4; ++nt) {
      int col = n0 + wn + nt * 16 + lr;
      float bcol = bias[col];
      if (mode != 2) {
#pragma unroll
        for (int r = 0; r < 4; ++r) {
          int row = m0 + wm + mt * 16 + lg * 4 + r;
          out[(size_t)row * 1024 + col] = f2bf((acc[mt][nt][r] + bcol) * sc);
        }
      } else {
        int row0 = m0 + wm + mt * 16 + lg * 4;
        int b = row0 >> 9, n = row0 & 511;
        int h = col >> 6, d = col & 63;
        ushort4 pk;
        pk.x = f2bf(acc[mt][nt][0] + bcol);
        pk.y = f2bf(acc[mt][nt][1] + bcol);
        pk.z = f2bf(acc[mt][nt][2] + bcol);
        pk.w = f2bf(acc[mt][nt][3] + bcol);
        *reinterpret_cast<ushort4*>(out + ((size_t)(b * 16 + h) * 64 + d) * 512 + n) = pk;
      }
    }
  }
}

// ---------------------------------------------------------------------------
// K1b: qt = qh @ Wrk^T (unchanged from R3).
// ---------------------------------------------------------------------------
__global__ __launch_bounds__(256) void k_qt(
    const uint16_t* __restrict__ qh, const uint16_t* __restrict__ WrkB,
    uint16_t* __restrict__ qt) {
  int t = threadIdx.x, lane = t & 63, w = t >> 6, lr = lane & 15, lg = lane >> 4;
  int row0 = blockIdx.x * 64 + w * 16;
  f32x4 acc[8];
#pragma unroll
  for (int i = 0; i < 8; ++i) acc[i] = (f32x4){0.f, 0.f, 0.f, 0.f};
  s16x8 af[2];
#pragma unroll
  for (int kk = 0; kk < 2; ++kk)
    af[kk] = *(const s16x8*)(qh + (size_t)(row0 + lr) * 64 + kk * 32 + lg * 8);
#pragma unroll
  for (int rt = 0; rt < 8; ++rt) {
#pragma unroll
    for (int kk = 0; kk < 2; ++kk) {
      s16x8 bf = *(const s16x8*)(WrkB + (size_t)(rt * 16 + lr) * 64 + kk * 32 + lg * 8);
      acc[rt] = MFMA16(af[kk], bf, acc[rt]);
    }
  }
#pragma unroll
  for (int rt = 0; rt < 8; ++rt)
#pragma unroll
    for (int r = 0; r < 4; ++r)
      qt[(size_t)(row0 + lg * 4 + r) * 128 + rt * 16 + lr] = f2bf(acc[rt][r]);
}

// ---------------------------------------------------------------------------
// K2: S1[bm][h][n_sw] (fp16) = qh . kh^T, batched per (b,h), dense MFMA.
// n_sw = n ^ ((h&7)<<3) so k_s2v2 can stage each bm's 16KB slice linearly.
// grid (mt=8, h=16, b=4); wave w owns m-rows [mt*64 + w*16, +16).
// ---------------------------------------------------------------------------
__global__ __launch_bounds__(256, 2) void k_score1(
    const uint16_t* __restrict__ qh, const uint16_t* __restrict__ kh,
    uint16_t* __restrict__ S1) {
  int t = threadIdx.x, lane = t & 63, w = t >> 6, lr = lane & 15, lg = lane >> 4;
  int mt = blockIdx.x, h = blockIdx.y, b = blockIdx.z;
  int mrow = b * 512 + mt * 64 + w * 16 + lr;
  const uint16_t* qrow = qh + (size_t)mrow * 1024 + h * 64 + lg * 8;
  s16x8 bq0 = *(const s16x8*)(qrow);
  s16x8 bq1 = *(const s16x8*)(qrow + 32);
  const uint16_t* krow = kh + ((size_t)b * 512 + lr) * 1024 + h * 64 + lg * 8;
  f32x4 acc[32];
#pragma unroll
  for (int i = 0; i < 32; ++i) acc[i] = (f32x4){0.f, 0.f, 0.f, 0.f};
#pragma unroll
  for (int g = 0; g < 4; ++g) {
    s16x8 ka[8][2];
#pragma unroll
    for (int i = 0; i < 8; ++i) {
      const uint16_t* p = krow + (size_t)((g * 8 + i) * 16) * 1024;
      ka[i][0] = *(const s16x8*)(p);
      ka[i][1] = *(const s16x8*)(p + 32);
    }
#pragma unroll
    for (int i = 0; i < 8; ++i) {
      acc[g * 8 + i] = MFMA16(ka[i][0], bq0, acc[g * 8 + i]);
      acc[g * 8 + i] = MFMA16(ka[i][1], bq1, acc[g * 8 + i]);
    }
  }
#pragma unroll
  for (int nt = 0; nt < 32; ++nt) {
    int nsw = (nt * 16 + lg * 4) ^ ((h & 7) << 3);
    ushort4 u;
    u.x = f2h(acc[nt][0]); u.y = f2h(acc[nt][1]);
    u.z = f2h(acc[nt][2]); u.w = f2h(acc[nt][3]);
    *(ushort4*)(S1 + (size_t)mrow * 8192 + h * 512 + nsw) = u;
  }
}

// ---------------------------------------------------------------------------
// K3: per-(b,m) relation streams, gll-pipelined. 2048 blocks x 256 thr.
// SATT holds S1(fp16,swizzled-n) on entry; holds att(bf16,swizzled-n) on exit.
// ---------------------------------------------------------------------------
#define STAGE(lbuf, gsrc)                                                    \
  { _Pragma("unroll")                                                        \
    for (int i_ = 0; i_ < 4; ++i_)                                           \
      gll16((const char*)(gsrc) + i_ * 4096 + t * 16,                        \
            (char*)(lbuf) + i_ * 4096 + t * 16); }

#define RK_CHUNK(c, idx)                                                     \
  {                                                                          \
    if ((c) < 14) { asm volatile("s_waitcnt vmcnt(4)" ::: "memory"); }       \
    else          { asm volatile("s_waitcnt vmcnt(0)" ::: "memory"); }       \
    __builtin_amdgcn_s_barrier();                                            \
    asm volatile("" ::: "memory");                                           \
    {                                                                        \
      int mine = (((2 * (c)) & 3) == w) ? 0                                  \
               : ((((2 * (c) + 1) & 3) == w) ? 1 : -1);                      \
      if (mine >= 0) {                                                       \
        const float* base_ = &stg[(c) & 1][(mine * 16 + lr) * 128 + lg * 8]; \
        _Pragma("unroll")                                                    \
        for (int kk = 0; kk < 4; ++kk) {                                     \
          float4 v0 = *(const float4*)(base_ + kk * 32);                     \
          float4 v1 = *(const float4*)(base_ + kk * 32 + 4);                 \
          acc[idx] = MFMA16(aqt[kk], pack8(v0, v1), acc[idx]);               \
        }                                                                    \
      }                                                                      \
    }                                                                        \
    asm volatile("s_waitcnt lgkmcnt(0)" ::: "memory");                       \
    __builtin_amdgcn_sched_barrier(0);                                       \
    __builtin_amdgcn_s_barrier();                                            \
    asm volatile("" ::: "memory");                                           \
    if ((c) < 14) { STAGE(stg[(c) & 1], rkb + ((c) + 2) * 16384) }           \
  }

__global__ __launch_bounds__(256, 3) void k_s2v2(
    const uint16_t* __restrict__ qt, const float* __restrict__ rk,
    const float* __restrict__ rv, uint16_t* SATT,
    const uint16_t* __restrict__ WrvT, const float* __restrict__ brv,
    uint16_t* __restrict__ V2) {
  int bm = blockIdx.x;
  int t = threadIdx.x, lane = t & 63, w = t >> 6, lr = lane & 15, lg = lane >> 4;
  __shared__ alignas(16) float stg[2][4096];        // 2 x 16KB stream chunks
  __shared__ alignas(16) uint16_t att_lds[16 * 512];  // S1 (fp16) then att (bf16)
  __shared__ alignas(16) uint16_t arv_lds[16 * 128];
  __shared__ float red[2][16][4];

  s16x8 aqt[4];
#pragma unroll
  for (int kk = 0; kk < 4; ++kk)
    aqt[kk] = *(const s16x8*)(qt + ((size_t)bm * 16 + lr) * 128 + kk * 32 + lg * 8);

  // stage S1 slice (16KB, linear) into att_lds
  const char* s1g = (const char*)(SATT + (size_t)bm * 8192);
#pragma unroll
  for (int i = 0; i < 4; ++i)
    gll16(s1g + i * 4096 + t * 16, (char*)att_lds + i * 4096 + t * 16);

  const char* rkb = (const char*)(rk + (size_t)bm * 65536);
  STAGE(stg[0], rkb)
  STAGE(stg[1], rkb + 16384)

  f32x4 acc[8];
#pragma unroll
  for (int j = 0; j < 8; ++j) acc[j] = (f32x4){0.f, 0.f, 0.f, 0.f};

  // ---- rk stream: 16 chunks, fully unrolled (static acc indices)
  RK_CHUNK(0, 0)  RK_CHUNK(1, 0)  RK_CHUNK(2, 1)  RK_CHUNK(3, 1)
  RK_CHUNK(4, 2)  RK_CHUNK(5, 2)  RK_CHUNK(6, 3)  RK_CHUNK(7, 3)
  RK_CHUNK(8, 4)  RK_CHUNK(9, 4)  RK_CHUNK(10, 5) RK_CHUNK(11, 5)
  RK_CHUNK(12, 6) RK_CHUNK(13, 6) RK_CHUNK(14, 7) RK_CHUNK(15, 7)

  // ---- S1 add (fp16 from att_lds)
#pragma unroll
  for (int idx = 0; idx < 8; ++idx) {
#pragma unroll
    for (int r = 0; r < 4; ++r) {
      int h = lg * 4 + r;
      int n = idx * 64 + w * 16 + lr;
      uint16_t s1v = *(const uint16_t*)((const char*)att_lds + h * 1024 +
                     (((uint32_t)n * 2) ^ ((uint32_t)(h & 7) << 4)));
      acc[idx][r] += h2f(s1v);
    }
  }

  // ---- softmax (rows h = lg*4+r, cols n = idx*64 + w*16 + lr)
  float mrow[4], inv[4];
#pragma unroll
  for (int r = 0; r < 4; ++r) {
    float mx = acc[0][r];
#pragma unroll
    for (int j = 1; j < 8; ++j) mx = fmaxf(mx, acc[j][r]);
#pragma unroll
    for (int off = 1; off < 16; off <<= 1) mx = fmaxf(mx, __shfl_xor(mx, off, 64));
    mrow[r] = mx;
  }
  if (lr == 0) {
#pragma unroll
    for (int r = 0; r < 4; ++r) red[0][lg * 4 + r][w] = mrow[r];
  }
  __syncthreads();
#pragma unroll
  for (int r = 0; r < 4; ++r) {
    const float* p = red[0][lg * 4 + r];
    mrow[r] = fmaxf(fmaxf(p[0], p[1]), fmaxf(p[2], p[3]));
  }
#pragma unroll
  for (int r = 0; r < 4; ++r) {
    float s = 0.f;
#pragma unroll
    for (int j = 0; j < 8; ++j) {
      float pj = __expf(acc[j][r] - mrow[r]);
      acc[j][r] = pj;
      s += pj;
    }
#pragma unroll
    for (int off = 1; off < 16; off <<= 1) s += __shfl_xor(s, off, 64);
    inv[r] = s;
  }
  if (lr == 0) {
#pragma unroll
    for (int r = 0; r < 4; ++r) red[1][lg * 4 + r][w] = inv[r];
  }
  __syncthreads();
#pragma unroll
  for (int r = 0; r < 4; ++r) {
    const float* p = red[1][lg * 4 + r];
    inv[r] = 1.f / (p[0] + p[1] + p[2] + p[3]);
  }
#pragma unroll
  for (int r = 0; r < 4; ++r) {
    int h = lg * 4 + r;
#pragma unroll
    for (int idx = 0; idx < 8; ++idx) {
      int n = idx * 64 + w * 16 + lr;
      uint32_t off = (uint32_t)h * 1024 + (((uint32_t)n * 2) ^ ((uint32_t)(h & 7) << 4));
      *(uint16_t*)((char*)att_lds + off) = f2bf(acc[idx][r] * inv[r]);
    }
  }
  __syncthreads();

  // ---- rv stream: arv[h][rc] = sum_n att[h,n] * rv[n,rc]
  const char* rvb = (const char*)(rv + (size_t)bm * 65536);
  f32x4 arv0 = (f32x4){0.f, 0.f, 0.f, 0.f}, arv1 = arv0;
  STAGE(stg[0], rvb)
  STAGE(stg[1], rvb + 16384)
#pragma unroll 1
  for (int c = 0; c < 16; ++c) {
    if (c < 14) { asm volatile("s_waitcnt vmcnt(4)" ::: "memory"); }
    else        { asm volatile("s_waitcnt vmcnt(0)" ::: "memory"); }
    __builtin_amdgcn_s_barrier();
    asm volatile("" ::: "memory");
    s16x8 a = *(const s16x8*)((const char*)att_lds + lr * 1024 +
              (((uint32_t)(c * 64 + lg * 16)) ^ ((uint32_t)(lr & 7) << 4)));
    const float* bb = &stg[c & 1][(lg * 8) * 128 + w * 32 + lr];
    s16x8 bf0, bf1;
#pragma unroll
    for (int i = 0; i < 8; ++i) bf0[i] = (short)f2bf(bb[i * 128]);
#pragma unroll
    for (int i = 0; i < 8; ++i) bf1[i] = (short)f2bf(bb[i * 128 + 16]);
    arv0 = MFMA16(a, bf0, arv0);
    arv1 = MFMA16(a, bf1, arv1);
    asm volatile("s_waitcnt lgkmcnt(0)" ::: "memory");
    __builtin_amdgcn_sched_barrier(0);
    __builtin_amdgcn_s_barrier();
    asm volatile("" ::: "memory");
    if (c < 14) { STAGE(stg[c & 1], rvb + (c + 2) * 16384) }
  }

  // ---- arv -> LDS, val2 = arv @ Wrv + brv -> V2
#pragma unroll
  for (int r = 0; r < 4; ++r) {
    int h = lg * 4 + r;
    uint32_t rc0 = (uint32_t)(w * 32 + lr) * 2;
    uint32_t rc1 = (uint32_t)(w * 32 + 16 + lr) * 2;
    *(uint16_t*)((char*)arv_lds + h * 256 + (rc0 ^ ((uint32_t)(h & 7) << 4))) = f2bf(arv0[r]);
    *(uint16_t*)((char*)arv_lds + h * 256 + (rc1 ^ ((uint32_t)(h & 7) << 4))) = f2bf(arv1[r]);
  }
  __syncthreads();
  f32x4 vacc = (f32x4){0.f, 0.f, 0.f, 0.f};
#pragma unroll
  for (int kk = 0; kk < 4; ++kk) {
    uint32_t rb = (uint32_t)(kk * 32 + lg * 8) * 2;
    s16x8 a = *(const s16x8*)((const char*)arv_lds + lr * 256 +
                              (rb ^ ((uint32_t)(lr & 7) << 4)));
    s16x8 bfw = *(const s16x8*)(WrvT + (size_t)(w * 16 + lr) * 128 + kk * 32 + lg * 8);
    vacc = MFMA16(a, bfw, vacc);
  }
  float bias = brv[w * 16 + lr];
#pragma unroll
  for (int r = 0; r < 4; ++r)
    V2[(size_t)bm * 1024 + (lg * 4 + r) * 64 + w * 16 + lr] = f2bf(vacc[r] + bias);

  // ---- att (bf16) -> global, in place over S1 (linear 16KB copy)
#pragma unroll
  for (int i = 0; i < 4; ++i) {
    s16x8 vv = *(const s16x8*)((const char*)att_lds + i * 4096 + t * 16);
    *(s16x8*)((char*)SATT + (size_t)bm * 16384 + i * 4096 + t * 16) = vv;
  }
}

// ---------------------------------------------------------------------------
// K4: val = att @ vh + V2 -> VALB. Batched per (b,h), grid (mt=4, h=16, b=4).
// Wave w owns m in [mt*128 + w*32, +32).
// ---------------------------------------------------------------------------
__global__ __launch_bounds__(256) void k_val1(
    const uint16_t* __restrict__ vhT, const uint16_t* __restrict__ ATT,
    const uint16_t* __restrict__ V2, uint16_t* __restrict__ VALB) {
  int t = threadIdx.x, lane = t & 63, w = t >> 6, lr = lane & 15, lg = lane >> 4;
  int mt = blockIdx.x, h = blockIdx.y, b = blockIdx.z;
  int mb = mt * 128 + w * 32;
  const uint16_t* vrow = vhT + ((size_t)((b * 16 + h) * 64) + lr) * 512 + lg * 8;
  const uint16_t* arow0 = ATT + (size_t)(b * 512 + mb + lr) * 8192 + h * 512;
  const uint16_t* arow1 = arow0 + (size_t)16 * 8192;
  f32x4 acc[2][4];
#pragma unroll
  for (int i = 0; i < 2; ++i)
#pragma unroll
    for (int j = 0; j < 4; ++j) acc[i][j] = (f32x4){0.f, 0.f, 0.f, 0.f};
#pragma unroll 4
  for (int kk = 0; kk < 16; ++kk) {
    int nsw = (kk * 32 + lg * 8) ^ ((h & 7) << 3);
    s16x8 a0 = *(const s16x8*)(arow0 + nsw);
    s16x8 a1 = *(const s16x8*)(arow1 + nsw);
#pragma unroll
    for (int dt = 0; dt < 4; ++dt) {
      s16x8 vf = *(const s16x8*)(vrow + (size_t)dt * 16 * 512 + kk * 32);
      acc[0][dt] = MFMA16(vf, a0, acc[0][dt]);
      acc[1][dt] = MFMA16(vf, a1, acc[1][dt]);
    }
  }
#pragma unroll
  for (int ml = 0; ml < 2; ++ml) {
#pragma unroll
    for (int dt = 0; dt < 4; ++dt) {
      size_t adr = (size_t)(b * 512 + mb + ml * 16 + lr) * 1024 + h * 64 + dt * 16 + lg * 4;
      ushort4 v2v = *(const ushort4*)(V2 + adr);
      ushort4 o;
      o.x = f2bf(acc[ml][dt][0] + bf2f(v2v.x));
      o.y = f2bf(acc[ml][dt][1] + bf2f(v2v.y));
      o.z = f2bf(acc[ml][dt][2] + bf2f(v2v.z));
      o.w = f2bf(acc[ml][dt][3] + bf2f(v2v.w));
      *(ushort4*)(VALB + adr) = o;
    }
  }
}

// ---------------------------------------------------------------------------
// K5: out = VAL @ Wo + bo (unchanged from R3).
// ---------------------------------------------------------------------------
__global__ __launch_bounds__(256) void k_out(
    const uint16_t* __restrict__ A, const uint16_t* __restrict__ WT,
    const float* __restrict__ bias, float* __restrict__ out) {
  __shared__ alignas(16) uint16_t As[128 * 64];
  __shared__ alignas(16) uint16_t Bs[128 * 64];
  int t = threadIdx.x, lane = t & 63, w = t >> 6, lr = lane & 15, lg = lane >> 4;
  int m0 = blockIdx.x * 128, n0 = blockIdx.y * 128;
  int wm = (w >> 1) * 64, wn = (w & 1) * 64;
  f32x4 acc[4][4];
#pragma unroll
  for (int i = 0; i < 4; ++i)
#pragma unroll
    for (int j = 0; j < 4; ++j) acc[i][j] = (f32x4){0.f, 0.f, 0.f, 0.f};
  int srow = t >> 1, sh = t & 1;
  for (int ko = 0; ko < 16; ++ko) {
    __syncthreads();
    {
      const uint16_t* asrc = A + (size_t)(m0 + srow) * 1024 + ko * 64 + sh * 32;
      const uint16_t* bsrc = WT + (size_t)(n0 + srow) * 1024 + ko * 64 + sh * 32;
#pragma unroll
      for (int c = 0; c < 4; ++c) {
        s16x8 va = *(const s16x8*)(asrc + c * 8);
        *reinterpret_cast<s16x8*>((char*)As + srow * 128 +
                                  ((((sh * 4 + c) * 16)) ^ ((srow & 7) << 4))) = va;
        s16x8 vb = *(const s16x8*)(bsrc + c * 8);
        *reinterpret_cast<s16x8*>((char*)Bs + srow * 128 + (sh * 4 + c) * 16) = vb;
      }
    }
    __syncthreads();
#pragma unroll
    for (int kk = 0; kk < 2; ++kk) {
      s16x8 af[4], bf[4];
#pragma unroll
      for (int mt = 0; mt < 4; ++mt) {
        int row = wm + mt * 16 + lr;
        af[mt] = *(const s16x8*)((const char*)As + row * 128 +
                                 (((kk * 32 + lg * 8) * 2) ^ ((row & 7) << 4)));
      }
#pragma unroll
      for (int nt = 0; nt < 4; ++nt) {
        int row = wn + nt * 16 + lr;
        bf[nt] = *(const s16x8*)((const char*)Bs + row * 128 +
                                 (((kk * 32 + lg * 8) * 2) ^ ((row & 7) << 4)));
      }
#pragma unroll
      for (int mt = 0; mt < 4; ++mt)
#pragma unroll
        for (int nt = 0; nt < 4; ++nt)
          acc[mt][nt] = MFMA16(af[mt], bf[nt], acc[mt][nt]);
    }
  }
#pragma unroll
  for (int mt = 0; mt < 4; ++mt) {
#pragma unroll
    for (int nt = 0; nt < 4; ++nt) {
      int col = n0 + wn + nt * 16 + lr;
      float bcol = bias[col];
#pragma unroll
      for (int r = 0; r < 4; ++r) {
        int row = m0 + wm + mt * 16 + lg * 4 + r;
        out[(size_t)row * 1024 + col] = acc[mt][nt][r] + bcol;
      }
    }
  }
}

// ---------------------------------------------------------------------------
// Fallback fused attention (R3 k_attn), used when ws_size < 74MB.
// ---------------------------------------------------------------------------
__device__ __forceinline__ uint32_t rv_sw(int r, uint32_t nbyte) {
  return nbyte ^ ((uint32_t)(r & 7) << 4) ^ ((uint32_t)(r & 24) << 2);
}

__global__ __launch_bounds__(256, 3) void k_attn_fb(
    const uint16_t* __restrict__ qh, const uint16_t* __restrict__ kh,
    const uint16_t* __restrict__ vhT, const uint16_t* __restrict__ qt,
    const float* __restrict__ rk, const float* __restrict__ rv,
    const uint16_t* __restrict__ WrvT, const float* __restrict__ brv,
    uint16_t* __restrict__ VAL) {
  int bm = (blockIdx.x & 7) * 256 + (blockIdx.x >> 3);
  int b = bm >> 9;
  int t = threadIdx.x, lane = t & 63, w = t >> 6, lr = lane & 15, lg = lane >> 4;
  __shared__ alignas(16) uint16_t qh_lds[16 * 64];
  __shared__ alignas(16) uint16_t att_lds[16 * 512];
  __shared__ alignas(16) uint16_t arv_lds[16 * 128];
  __shared__ alignas(16) uint16_t rvT[128 * 64];
  __shared__ float red[2][16][4];
  const s16x8 z8 = {0, 0, 0, 0, 0, 0, 0, 0};

  for (int i = t; i < 1024; i += 256) qh_lds[i] = qh[(size_t)bm * 1024 + i];
  s16x8 aqt[4];
#pragma unroll
  for (int kk = 0; kk < 4; ++kk)
    aqt[kk] = *(const s16x8*)(qt + ((size_t)bm * 16 + lr) * 128 + kk * 32 + lg * 8);
  f32x4 acc[8];
#pragma unroll
  for (int j = 0; j < 8; ++j) acc[j] = (f32x4){0.f, 0.f, 0.f, 0.f};
  __syncthreads();
  int wn = w * 128;
  const float* rkb = rk + (size_t)bm * 65536;
#pragma unroll 4
  for (int j = 0; j < 8; ++j) {
    const float* rowp = rkb + (size_t)(wn + j * 16 + lr) * 128 + lg * 8;
#pragma unroll
    for (int kk = 0; kk < 4; ++kk) {
      float4 v0 = *(const float4*)(rowp + kk * 32);
      float4 v1 = *(const float4*)(rowp + kk * 32 + 4);
      acc[j] = MFMA16(aqt[kk], pack8(v0, v1), acc[j]);
    }
  }
  const uint16_t* khb = kh + (size_t)b * 512 * 1024;
  for (int kk = 0; kk < 32; ++kk) {
    s16x8 a = *(const s16x8*)(qh_lds + (kk >> 1) * 64 + (kk & 1) * 32 + lg * 8);
    s16x8 az = (lr == (kk >> 1)) ? a : z8;
#pragma unroll
    for (int j = 0; j < 8; ++j) {
      s16x8 bf = *(const s16x8*)(khb + (size_t)(wn + j * 16 + lr) * 1024 + kk * 32 + lg * 8);
      acc[j] = MFMA16(az, bf, acc[j]);
    }
  }
  float mrow[4], inv[4];
#pragma unroll
  for (int r = 0; r < 4; ++r) {
    float mx = acc[0][r];
#pragma unroll
    for (int j = 1; j < 8; ++j) mx = fmaxf(mx, acc[j][r]);
#pragma unroll
    for (int off = 1; off < 16; off <<= 1) mx = fmaxf(mx, __shfl_xor(mx, off, 64));
    mrow[r] = mx;
  }
  if (lr == 0) {
#pragma unroll
    for (int r = 0; r < 4; ++r) red[0][lg * 4 + r][w] = mrow[r];
  }
  __syncthreads();
#pragma unroll
  for (int r = 0; r < 4; ++r) {
    const float* p = red[0][lg * 4 + r];
    mrow[r] = fmaxf(fmaxf(p[0], p[1]), fmaxf(p[2], p[3]));
  }
#pragma unroll
  for (int r = 0; r < 4; ++r) {
    float s = 0.f;
#pragma unroll
    for (int j = 0; j < 8; ++j) {
      float pj = __expf(acc[j][r] - mrow[r]);
      acc[j][r] = pj;
      s += pj;
    }
#pragma unroll
    for (int off = 1; off < 16; off <<= 1) s += __shfl_xor(s, off, 64);
    inv[r] = s;
  }
  if (lr == 0) {
#pragma unroll
    for (int r = 0; r < 4; ++r) red[1][lg * 4 + r][w] = inv[r];
  }
  __syncthreads();
#pragma unroll
  for (int r = 0; r < 4; ++r) {
    const float* p = red[1][lg * 4 + r];
    inv[r] = 1.f / (p[0] + p[1] + p[2] + p[3]);
  }
#pragma unroll
  for (int r = 0; r < 4; ++r) {
    int h = lg * 4 + r;
#pragma unroll
    for (int j = 0; j < 8; ++j) {
      int n = wn + j * 16 + lr;
      uint32_t off = (uint32_t)h * 1024 + (((uint32_t)n * 2) ^ ((uint32_t)(h & 7) << 4));
      *(uint16_t*)((char*)att_lds + off) = f2bf(acc[j][r] * inv[r]);
    }
  }
  __syncthreads();
  int sn0 = (t >> 4) * 4;
  int sc0 = (t & 15) * 8;
  const float* rvb = rv + (size_t)bm * 65536;
  float4 vreg[4][2];
  {
    const float* p = rvb + (size_t)sn0 * 128 + sc0;
#pragma unroll
    for (int j = 0; j < 4; ++j) {
      vreg[j][0] = *(const float4*)(p + j * 128);
      vreg[j][1] = *(const float4*)(p + j * 128 + 4);
    }
  }
  f32x4 vacc0 = (f32x4){0.f, 0.f, 0.f, 0.f};
  f32x4 vacc1 = (f32x4){0.f, 0.f, 0.f, 0.f};
  const uint16_t* vtb = vhT + (size_t)b * 1024 * 512;
  for (int nk = 0; nk < 16; ++nk) {
    int nb = nk * 32 + lg * 8;
    s16x8 a = *(const s16x8*)((const char*)att_lds + lr * 1024 +
                              (((uint32_t)nb * 2) ^ ((uint32_t)(lr & 7) << 4)));
#pragma unroll
    for (int hp = 0; hp < 16; ++hp) {
      s16x8 az = (lr == hp) ? a : z8;
      s16x8 bf = *(const s16x8*)(vtb + (size_t)(hp * 64 + w * 16 + lr) * 512 + nb);
      if (hp & 1) vacc1 = MFMA16(az, bf, vacc1);
      else        vacc0 = MFMA16(az, bf, vacc0);
    }
  }
  f32x4 arv0 = (f32x4){0.f, 0.f, 0.f, 0.f}, arv1 = arv0;
  for (int ch = 0; ch < 8; ++ch) {
    __syncthreads();
#pragma unroll
    for (int cc = 0; cc < 8; ++cc) {
      int r = sc0 + cc;
      ushort4 u;
      u.x = f2bf(vreg[0][cc >> 2][cc & 3]);
      u.y = f2bf(vreg[1][cc >> 2][cc & 3]);
      u.z = f2bf(vreg[2][cc >> 2][cc & 3]);
      u.w = f2bf(vreg[3][cc >> 2][cc & 3]);
      *(ushort4*)((char*)rvT + r * 128 + rv_sw(r, (uint32_t)sn0 * 2)) = u;
    }
    __syncthreads();
    if (ch < 7) {
      const float* p = rvb + (size_t)((ch + 1) * 64 + sn0) * 128 + sc0;
#pragma unroll
      for (int j = 0; j < 4; ++j) {
        vreg[j][0] = *(const float4*)(p + j * 128);
        vreg[j][1] = *(const float4*)(p + j * 128 + 4);
      }
    }
#pragma unroll
    for (int kkl = 0; kkl < 2; ++kkl) {
      int kk = ch * 2 + kkl;
      int nb = kk * 32 + lg * 8;
      s16x8 a = *(const s16x8*)((const char*)att_lds + lr * 1024 +
                                (((uint32_t)nb * 2) ^ ((uint32_t)(lr & 7) << 4)));
      int nl2 = (kkl * 32 + lg * 8) * 2;
#pragma unroll
      for (int rt = 0; rt < 2; ++rt) {
        int rc = w * 32 + rt * 16 + lr;
        s16x8 bfr = *(const s16x8*)((const char*)rvT + rc * 128 + rv_sw(rc, (uint32_t)nl2));
        if (rt == 0) arv0 = MFMA16(a, bfr, arv0);
        else         arv1 = MFMA16(a, bfr, arv1);
      }
    }
  }
  f32x4 vacc;
#pragma unroll
  for (int r = 0; r < 4; ++r) vacc[r] = vacc0[r] + vacc1[r];
#pragma unroll
  for (int r = 0; r < 4; ++r) {
    int h = lg * 4 + r;
    uint32_t rc0 = (uint32_t)(w * 32 + lr) * 2;
    uint32_t rc1 = (uint32_t)(w * 32 + 16 + lr) * 2;
    *(uint16_t*)((char*)arv_lds + h * 256 + (rc0 ^ ((uint32_t)(h & 7) << 4))) = f2bf(arv0[r]);
    *(uint16_t*)((char*)arv_lds + h * 256 + (rc1 ^ ((uint32_t)(h & 7) << 4))) = f2bf(arv1[r]);
  }
  __syncthreads();
#pragma unroll
  for (int kk = 0; kk < 4; ++kk) {
    uint32_t rb = (uint32_t)(kk * 32 + lg * 8) * 2;
    s16x8 a = *(const s16x8*)((const char*)arv_lds + lr * 256 +
                              (rb ^ ((uint32_t)(lr & 7) << 4)));
    s16x8 bf = *(const s16x8*)(WrvT + (size_t)(w * 16 + lr) * 128 + kk * 32 + lg * 8);
    vacc = MFMA16(a, bf, vacc);
  }
  float bias = brv[w * 16 + lr];
#pragma unroll
  for (int r = 0; r < 4; ++r)
    VAL[(size_t)bm * 1024 + (lg * 4 + r) * 64 + w * 16 + lr] = f2bf(vacc[r] + bias);
}

// ---------------------------------------------------------------------------
extern "C" void kernel_launch(void* const* d_in, const int* in_sizes, int n_in,
                              void* d_out, int out_size, void* d_ws, size_t ws_size,
                              hipStream_t stream) {
  const float* q   = (const float*)d_in[0];
  const float* k_  = (const float*)d_in[1];
  const float* v   = (const float*)d_in[2];
  const float* r_k = (const float*)d_in[3];
  const float* r_v = (const float*)d_in[4];
  const float* Wq  = (const float*)d_in[5];
  const float* bq  = (const float*)d_in[6];
  const float* Wk  = (const float*)d_in[7];
  const float* bk  = (const float*)d_in[8];
  const float* Wv  = (const float*)d_in[9];
  const float* bv  = (const float*)d_in[10];
  const float* Wrk = (const float*)d_in[11];
  // d_in[12] = brk: softmax-invariant, unused
  const float* Wrv = (const float*)d_in[13];
  const float* brv = (const float*)d_in[14];
  const float* Wo  = (const float*)d_in[15];
  const float* bo  = (const float*)d_in[16];
  (void)in_sizes; (void)n_in; (void)out_size;

  char* ws = (char*)d_ws;
  uint16_t* WqT  = (uint16_t*)(ws + (size_t)(0));
  uint16_t* WkT  = (uint16_t*)(ws + (size_t)(2u << 20));
  uint16_t* WvT  = (uint16_t*)(ws + (size_t)(4u << 20));
  uint16_t* WoT  = (uint16_t*)(ws + (size_t)(6u << 20));
  uint16_t* WrkB = (uint16_t*)(ws + (size_t)(8u << 20));
  uint16_t* WrvT = (uint16_t*)(ws + (size_t)(8u << 20) + (64u << 10));
  uint16_t* QH   = (uint16_t*)(ws + (size_t)(16u << 20));
  uint16_t* KH   = (uint16_t*)(ws + (size_t)(20u << 20));
  uint16_t* VHT  = (uint16_t*)(ws + (size_t)(24u << 20));
  uint16_t* QT   = (uint16_t*)(ws + (size_t)(28u << 20));
  uint16_t* VALB = (uint16_t*)(ws + (size_t)(36u << 20));
  if (ws_size < (size_t)(40u << 20)) return;

  dim3 blk(256, 1, 1);
  k_prep<<<dim3(256, 5, 1), blk, 0, stream>>>(Wq, Wk, Wv, Wo, Wrk, Wrv,
                                              WqT, WkT, WvT, WoT, WrkB, WrvT);
  k_projqkv<<<dim3(16, 8, 3), blk, 0, stream>>>(q, k_, v, WqT, bq, bk, bv, QH);
  k_qt<<<dim3(512, 1, 1), blk, 0, stream>>>(QH, WrkB, QT);

  if (ws_size >= (size_t)(74u << 20)) {
    uint16_t* V2   = (uint16_t*)(ws + (size_t)(16u << 20));  // QH slot (dead after score1)
    uint16_t* SATT = (uint16_t*)(ws + (size_t)(40u << 20));  // 33.6 MB
    k_score1<<<dim3(8, 16, 4), blk, 0, stream>>>(QH, KH, SATT);
    k_s2v2<<<dim3(2048, 1, 1), blk, 0, stream>>>(QT, r_k, r_v, SATT, WrvT, brv, V2);
    k_val1<<<dim3(4, 16, 4), blk, 0, stream>>>(VHT, SATT, V2, VALB);
  } else {
    k_attn_fb<<<dim3(2048, 1, 1), blk, 0, stream>>>(QH, KH, VHT, QT, r_k, r_v,
                                                    WrvT, brv, VALB);
  }
  k_out<<<dim3(16, 8, 1), blk, 0, stream>>>(VALB, WoT, bo, (float*)d_out);
}

// Round 5
// 380.010 us; speedup vs baseline: 2.0730x; 1.4694x over previous
//
#include <hip/hip_runtime.h>
#include <hip/hip_bf16.h>
#include <hip/hip_fp16.h>
#include <stdint.h>

// RelationMultiHeadAttention on MI355X.
// R5: k_s2v2 rebuilt with wave-private, barrier-free gll streams.
//   rk: 32 steps x 2KB/wave, 4-deep, vmcnt(6), swizzled-source (conflict-free reads)
//   rv: 16 chunks x 4KB/wave (gathered rc-slice), 2-deep, vmcnt(4)
// Pipeline: k_prep -> k_projqkv -> k_qt -> k_score1 -> k_s2v2 -> k_val1 -> k_out

typedef __attribute__((ext_vector_type(4))) float f32x4;
typedef __attribute__((ext_vector_type(8))) short s16x8;

#define MFMA16(A, B, C) __builtin_amdgcn_mfma_f32_16x16x32_bf16(A, B, C, 0, 0, 0)

__device__ __forceinline__ uint16_t f2bf(float x) {
  uint32_t u = __float_as_uint(x);
  u += 0x7fffu + ((u >> 16) & 1u);
  return (uint16_t)(u >> 16);
}
__device__ __forceinline__ float bf2f(uint16_t u) {
  return __uint_as_float((uint32_t)u << 16);
}
__device__ __forceinline__ uint16_t f2h(float x) {
  __half h = __float2half_rn(x);
  return *reinterpret_cast<uint16_t*>(&h);
}
__device__ __forceinline__ float h2f(uint16_t u) {
  __half h = *reinterpret_cast<__half*>(&u);
  return __half2float(h);
}

__device__ __forceinline__ s16x8 pack8(float4 a, float4 b) {
  s16x8 r;
  r[0] = (short)f2bf(a.x); r[1] = (short)f2bf(a.y); r[2] = (short)f2bf(a.z); r[3] = (short)f2bf(a.w);
  r[4] = (short)f2bf(b.x); r[5] = (short)f2bf(b.y); r[6] = (short)f2bf(b.z); r[7] = (short)f2bf(b.w);
  return r;
}

__device__ __forceinline__ void gll16(const void* g, void* l) {
  __builtin_amdgcn_global_load_lds(
      (const __attribute__((address_space(1))) uint32_t*)(g),
      (__attribute__((address_space(3))) uint32_t*)(l), 16, 0, 0);
}

// ---------------------------------------------------------------------------
// K0: weight prep (unchanged).
// ---------------------------------------------------------------------------
__global__ __launch_bounds__(256) void k_prep(
    const float* __restrict__ Wq, const float* __restrict__ Wk,
    const float* __restrict__ Wv, const float* __restrict__ Wo,
    const float* __restrict__ Wrk, const float* __restrict__ Wrv,
    uint16_t* __restrict__ WqT, uint16_t* __restrict__ WkT,
    uint16_t* __restrict__ WvT, uint16_t* __restrict__ WoT,
    uint16_t* __restrict__ WrkB, uint16_t* __restrict__ WrvT) {
  int z = blockIdx.y;
  int t = threadIdx.x;
  if (z == 4) {
    if (blockIdx.x == 0) {
      for (int i = t; i < 128 * 64; i += 256) WrkB[i] = f2bf(Wrk[i]);
      for (int i = t; i < 64 * 128; i += 256) {
        int d = i >> 7, r = i & 127;
        WrvT[i] = f2bf(Wrv[r * 64 + d]);
      }
    }
    return;
  }
  const float* W = (z == 0) ? Wq : (z == 1) ? Wk : (z == 2) ? Wv : Wo;
  uint16_t* O = (z == 0) ? WqT : (z == 1) ? WkT : (z == 2) ? WvT : WoT;
  int tk = (blockIdx.x >> 4) * 64;
  int tn = (blockIdx.x & 15) * 64;
  __shared__ float tile[64][65];
  {
    int kk = t >> 2, c0 = (t & 3) * 16;
    const float* src = W + (size_t)(tk + kk) * 1024 + tn + c0;
#pragma unroll
    for (int i = 0; i < 16; i += 4) {
      float4 v = *(const float4*)(src + i);
      tile[kk][c0 + i + 0] = v.x; tile[kk][c0 + i + 1] = v.y;
      tile[kk][c0 + i + 2] = v.z; tile[kk][c0 + i + 3] = v.w;
    }
  }
  __syncthreads();
  {
    int n_loc = t >> 2;
    int n = tn + n_loc;
#pragma unroll
    for (int cc = 0; cc < 2; ++cc) {
      int c = (t & 3) * 2 + cc;
      int csrc = c ^ (n & 7);
      s16x8 pk;
#pragma unroll
      for (int j = 0; j < 8; ++j) pk[j] = (short)f2bf(tile[csrc * 8 + j][n_loc]);
      *reinterpret_cast<s16x8*>(O + (size_t)n * 1024 + tk + c * 8) = pk;
    }
  }
}

// ---------------------------------------------------------------------------
// K1: projections (unchanged).
// ---------------------------------------------------------------------------
__global__ __launch_bounds__(256) void k_projqkv(
    const float* __restrict__ Xq, const float* __restrict__ Xk,
    const float* __restrict__ Xv, const uint16_t* __restrict__ WTbase,
    const float* __restrict__ bq, const float* __restrict__ bk,
    const float* __restrict__ bv, uint16_t* __restrict__ outbase) {
  int mode = blockIdx.z;
  const float* X = (mode == 0) ? Xq : (mode == 1) ? Xk : Xv;
  const float* bias = (mode == 0) ? bq : (mode == 1) ? bk : bv;
  const uint16_t* WT = WTbase + (size_t)mode * (1u << 20);
  uint16_t* out = outbase + (size_t)mode * (2u << 20);

  __shared__ alignas(16) uint16_t As[128 * 64];
  __shared__ alignas(16) uint16_t Bs[128 * 64];
  int t = threadIdx.x, lane = t & 63, w = t >> 6, lr = lane & 15, lg = lane >> 4;
  int m0 = blockIdx.x * 128, n0 = blockIdx.y * 128;
  int wm = (w >> 1) * 64, wn = (w & 1) * 64;
  f32x4 acc[4][4];
#pragma unroll
  for (int i = 0; i < 4; ++i)
#pragma unroll
    for (int j = 0; j < 4; ++j) acc[i][j] = (f32x4){0.f, 0.f, 0.f, 0.f};
  int srow = t >> 1, sh = t & 1;
  for (int ko = 0; ko < 16; ++ko) {
    __syncthreads();
    {
      const float* src = X + (size_t)(m0 + srow) * 1024 + ko * 64 + sh * 32;
#pragma unroll
      for (int c = 0; c < 4; ++c) {
        float4 v0 = *(const float4*)(src + c * 8);
        float4 v1 = *(const float4*)(src + c * 8 + 4);
        s16x8 pk = pack8(v0, v1);
        *reinterpret_cast<s16x8*>((char*)As + srow * 128 +
                                  ((((sh * 4 + c) * 16)) ^ ((srow & 7) << 4))) = pk;
      }
      const uint16_t* bsrc = WT + (size_t)(n0 + srow) * 1024 + ko * 64 + sh * 32;
#pragma unroll
      for (int c = 0; c < 4; ++c) {
        s16x8 vb = *(const s16x8*)(bsrc + c * 8);
        *reinterpret_cast<s16x8*>((char*)Bs + srow * 128 + (sh * 4 + c) * 16) = vb;
      }
    }
    __syncthreads();
#pragma unroll
    for (int kk = 0; kk < 2; ++kk) {
      s16x8 af[4], bf[4];
#pragma unroll
      for (int mt = 0; mt < 4; ++mt) {
        int row = wm + mt * 16 + lr;
        af[mt] = *(const s16x8*)((const char*)As + row * 128 +
                                 (((kk * 32 + lg * 8) * 2) ^ ((row & 7) << 4)));
      }
#pragma unroll
      for (int nt = 0; nt < 4; ++nt) {
        int row = wn + nt * 16 + lr;
        bf[nt] = *(const s16x8*)((const char*)Bs + row * 128 +
                                 (((kk * 32 + lg * 8) * 2) ^ ((row & 7) << 4)));
      }
#pragma unroll
      for (int mt = 0; mt < 4; ++mt)
#pragma unroll
        for (int nt = 0; nt < 4; ++nt)
          acc[mt][nt] = MFMA16(af[mt], bf[nt], acc[mt][nt]);
    }
  }
  float sc = (mode == 1) ? 0.125f : 1.0f;
#pragma unroll
  for (int mt = 0; mt < 4; ++mt) {
#pragma unroll
    for (int nt = 0; nt < 4; ++nt) {
      int col = n0 + wn + nt * 16 + lr;
      float bcol = bias[col];
      if (mode != 2) {
#pragma unroll
        for (int r = 0; r < 4; ++r) {
          int row = m0 + wm + mt * 16 + lg * 4 + r;
          out[(size_t)row * 1024 + col] = f2bf((acc[mt][nt][r] + bcol) * sc);
        }
      } else {
        int row0 = m0 + wm + mt * 16 + lg * 4;
        int b = row0 >> 9, n = row0 & 511;
        int h = col >> 6, d = col & 63;
        ushort4 pk;
        pk.x = f2bf(acc[mt][nt][0] + bcol);
        pk.y = f2bf(acc[mt][nt][1] + bcol);
        pk.z = f2bf(acc[mt][nt][2] + bcol);
        pk.w = f2bf(acc[mt][nt][3] + bcol);
        *reinterpret_cast<ushort4*>(out + ((size_t)(b * 16 + h) * 64 + d) * 512 + n) = pk;
      }
    }
  }
}

// ---------------------------------------------------------------------------
// K1b: qt = qh @ Wrk^T (unchanged).
// ---------------------------------------------------------------------------
__global__ __launch_bounds__(256) void k_qt(
    const uint16_t* __restrict__ qh, const uint16_t* __restrict__ WrkB,
    uint16_t* __restrict__ qt) {
  int t = threadIdx.x, lane = t & 63, w = t >> 6, lr = lane & 15, lg = lane >> 4;
  int row0 = blockIdx.x * 64 + w * 16;
  f32x4 acc[8];
#pragma unroll
  for (int i = 0; i < 8; ++i) acc[i] = (f32x4){0.f, 0.f, 0.f, 0.f};
  s16x8 af[2];
#pragma unroll
  for (int kk = 0; kk < 2; ++kk)
    af[kk] = *(const s16x8*)(qh + (size_t)(row0 + lr) * 64 + kk * 32 + lg * 8);
#pragma unroll
  for (int rt = 0; rt < 8; ++rt) {
#pragma unroll
    for (int kk = 0; kk < 2; ++kk) {
      s16x8 bf = *(const s16x8*)(WrkB + (size_t)(rt * 16 + lr) * 64 + kk * 32 + lg * 8);
      acc[rt] = MFMA16(af[kk], bf, acc[rt]);
    }
  }
#pragma unroll
  for (int rt = 0; rt < 8; ++rt)
#pragma unroll
    for (int r = 0; r < 4; ++r)
      qt[(size_t)(row0 + lg * 4 + r) * 128 + rt * 16 + lr] = f2bf(acc[rt][r]);
}

// ---------------------------------------------------------------------------
// K2: S1[bm][h][n_sw] (fp16) = qh . kh^T (unchanged).
// ---------------------------------------------------------------------------
__global__ __launch_bounds__(256, 2) void k_score1(
    const uint16_t* __restrict__ qh, const uint16_t* __restrict__ kh,
    uint16_t* __restrict__ S1) {
  int t = threadIdx.x, lane = t & 63, w = t >> 6, lr = lane & 15, lg = lane >> 4;
  int mt = blockIdx.x, h = blockIdx.y, b = blockIdx.z;
  int mrow = b * 512 + mt * 64 + w * 16 + lr;
  const uint16_t* qrow = qh + (size_t)mrow * 1024 + h * 64 + lg * 8;
  s16x8 bq0 = *(const s16x8*)(qrow);
  s16x8 bq1 = *(const s16x8*)(qrow + 32);
  const uint16_t* krow = kh + ((size_t)b * 512 + lr) * 1024 + h * 64 + lg * 8;
  f32x4 acc[32];
#pragma unroll
  for (int i = 0; i < 32; ++i) acc[i] = (f32x4){0.f, 0.f, 0.f, 0.f};
#pragma unroll
  for (int g = 0; g < 4; ++g) {
    s16x8 ka[8][2];
#pragma unroll
    for (int i = 0; i < 8; ++i) {
      const uint16_t* p = krow + (size_t)((g * 8 + i) * 16) * 1024;
      ka[i][0] = *(const s16x8*)(p);
      ka[i][1] = *(const s16x8*)(p + 32);
    }
#pragma unroll
    for (int i = 0; i < 8; ++i) {
      acc[g * 8 + i] = MFMA16(ka[i][0], bq0, acc[g * 8 + i]);
      acc[g * 8 + i] = MFMA16(ka[i][1], bq1, acc[g * 8 + i]);
    }
  }
#pragma unroll
  for (int nt = 0; nt < 32; ++nt) {
    int nsw = (nt * 16 + lg * 4) ^ ((h & 7) << 3);
    ushort4 u;
    u.x = f2h(acc[nt][0]); u.y = f2h(acc[nt][1]);
    u.z = f2h(acc[nt][2]); u.w = f2h(acc[nt][3]);
    *(ushort4*)(S1 + (size_t)mrow * 8192 + h * 512 + nsw) = u;
  }
}

// ---------------------------------------------------------------------------
// K3: per-(b,m) relation streams. Wave-private gll pipelines, no barriers.
// Wave w: rk rows n in {idx*64 + w*16 + [0,16)}; rv cols rc in [w*32, +32).
// rk LDS per step: [16 rows][8 c16], content[r][c] = global[r][c ^ (r&7)].
// ---------------------------------------------------------------------------
#define RKSTEP(s)                                                              \
  {                                                                            \
    asm volatile("s_waitcnt vmcnt(%0)" ::                                      \
                 "i"(((s) <= 27) ? 6 : (31 - (s)) * 2) : "memory");            \
    const char* bp_ = wpriv + ((s) & 3) * 2048 + lr * 128;                     \
    float4 v0_ = *(const float4*)(bp_ + (((lg * 2 + 0) ^ (lr & 7)) * 16));     \
    float4 v1_ = *(const float4*)(bp_ + (((lg * 2 + 1) ^ (lr & 7)) * 16));     \
    acc[(s) >> 2] = MFMA16(aqt[(s) & 3], pack8(v0_, v1_), acc[(s) >> 2]);      \
    if ((s) + 4 < 32) {                                                        \
      const int s2_ = (s) + 4;                                                 \
      const char* src_ = rkb + (size_t)((s2_ >> 2) * 64 + w * 16 + r_lo) * 512 \
                         + (s2_ & 3) * 128 + c16s * 16;                        \
      char* dst_ = wpriv + (s2_ & 3) * 2048 + lane * 16;                       \
      gll16(src_, dst_);                                                       \
      gll16(src_ + 8 * 512, dst_ + 1024);                                      \
    }                                                                          \
  }

__global__ __launch_bounds__(256, 3) void k_s2v2(
    const uint16_t* __restrict__ qt, const float* __restrict__ rk,
    const float* __restrict__ rv, uint16_t* SATT,
    const uint16_t* __restrict__ WrvT, const float* __restrict__ brv,
    uint16_t* __restrict__ V2) {
  int bm = blockIdx.x;
  int t = threadIdx.x, lane = t & 63, w = t >> 6, lr = lane & 15, lg = lane >> 4;
  __shared__ alignas(16) char stream_lds[32768];      // 8KB per wave, private
  __shared__ alignas(16) uint16_t att_lds[16 * 512];  // S1 fp16 -> att bf16
  __shared__ alignas(16) uint16_t arv_lds[16 * 128];
  __shared__ float red[2][16][4];
  char* wpriv = stream_lds + w * 8192;
  const int r_lo = lane >> 3;               // 0..7 within a gll row-group
  const int c16s = (lane & 7) ^ r_lo;       // swizzled source chunk

  // qt fragments + S1 staging; then drain so vmcnt counts only rk glls.
  s16x8 aqt[4];
#pragma unroll
  for (int kk = 0; kk < 4; ++kk)
    aqt[kk] = *(const s16x8*)(qt + ((size_t)bm * 16 + lr) * 128 + kk * 32 + lg * 8);
  const char* s1g = (const char*)(SATT + (size_t)bm * 8192);
#pragma unroll
  for (int i = 0; i < 4; ++i)
    gll16(s1g + i * 4096 + t * 16, (char*)att_lds + i * 4096 + t * 16);
  asm volatile("s_waitcnt vmcnt(0)" ::: "memory");

  // rk prologue: stage steps 0..3
  const char* rkb = (const char*)(rk + (size_t)bm * 65536);
#pragma unroll
  for (int s2 = 0; s2 < 4; ++s2) {
    const char* src_ = rkb + (size_t)((s2 >> 2) * 64 + w * 16 + r_lo) * 512 +
                       (s2 & 3) * 128 + c16s * 16;
    char* dst_ = wpriv + (s2 & 3) * 2048 + lane * 16;
    gll16(src_, dst_);
    gll16(src_ + 8 * 512, dst_ + 1024);
  }

  f32x4 acc[8];
#pragma unroll
  for (int j = 0; j < 8; ++j) acc[j] = (f32x4){0.f, 0.f, 0.f, 0.f};

  RKSTEP(0)  RKSTEP(1)  RKSTEP(2)  RKSTEP(3)  RKSTEP(4)  RKSTEP(5)  RKSTEP(6)  RKSTEP(7)
  RKSTEP(8)  RKSTEP(9)  RKSTEP(10) RKSTEP(11) RKSTEP(12) RKSTEP(13) RKSTEP(14) RKSTEP(15)
  RKSTEP(16) RKSTEP(17) RKSTEP(18) RKSTEP(19) RKSTEP(20) RKSTEP(21) RKSTEP(22) RKSTEP(23)
  RKSTEP(24) RKSTEP(25) RKSTEP(26) RKSTEP(27) RKSTEP(28) RKSTEP(29) RKSTEP(30) RKSTEP(31)

  // rv prefetch chunks 0,1 into this wave's (now free) region
  const char* rvb = (const char*)(rv + (size_t)bm * 65536);
#pragma unroll
  for (int c = 0; c < 2; ++c) {
#pragma unroll
    for (int g = 0; g < 4; ++g) {
      const char* src_ = rvb + (size_t)(c * 32 + g * 8 + r_lo) * 512 + w * 128 +
                         (lane & 7) * 16;
      gll16(src_, wpriv + c * 4096 + g * 1024 + lane * 16);
    }
  }
  __syncthreads();  // S1 (all waves' quarters) visible

  // ---- S1 add (fp16 from att_lds)
#pragma unroll
  for (int idx = 0; idx < 8; ++idx) {
#pragma unroll
    for (int r = 0; r < 4; ++r) {
      int h = lg * 4 + r;
      int n = idx * 64 + w * 16 + lr;
      uint16_t s1v = *(const uint16_t*)((const char*)att_lds + h * 1024 +
                     (((uint32_t)n * 2) ^ ((uint32_t)(h & 7) << 4)));
      acc[idx][r] += h2f(s1v);
    }
  }

  // ---- softmax (rows h = lg*4+r, cols n = idx*64 + w*16 + lr)
  float mrow[4], inv[4];
#pragma unroll
  for (int r = 0; r < 4; ++r) {
    float mx = acc[0][r];
#pragma unroll
    for (int j = 1; j < 8; ++j) mx = fmaxf(mx, acc[j][r]);
#pragma unroll
    for (int off = 1; off < 16; off <<= 1) mx = fmaxf(mx, __shfl_xor(mx, off, 64));
    mrow[r] = mx;
  }
  if (lr == 0) {
#pragma unroll
    for (int r = 0; r < 4; ++r) red[0][lg * 4 + r][w] = mrow[r];
  }
  __syncthreads();
#pragma unroll
  for (int r = 0; r < 4; ++r) {
    const float* p = red[0][lg * 4 + r];
    mrow[r] = fmaxf(fmaxf(p[0], p[1]), fmaxf(p[2], p[3]));
  }
#pragma unroll
  for (int r = 0; r < 4; ++r) {
    float s = 0.f;
#pragma unroll
    for (int j = 0; j < 8; ++j) {
      float pj = __expf(acc[j][r] - mrow[r]);
      acc[j][r] = pj;
      s += pj;
    }
#pragma unroll
    for (int off = 1; off < 16; off <<= 1) s += __shfl_xor(s, off, 64);
    inv[r] = s;
  }
  if (lr == 0) {
#pragma unroll
    for (int r = 0; r < 4; ++r) red[1][lg * 4 + r][w] = inv[r];
  }
  __syncthreads();
#pragma unroll
  for (int r = 0; r < 4; ++r) {
    const float* p = red[1][lg * 4 + r];
    inv[r] = 1.f / (p[0] + p[1] + p[2] + p[3]);
  }
#pragma unroll
  for (int r = 0; r < 4; ++r) {
    int h = lg * 4 + r;
#pragma unroll
    for (int idx = 0; idx < 8; ++idx) {
      int n = idx * 64 + w * 16 + lr;
      uint32_t off = (uint32_t)h * 1024 + (((uint32_t)n * 2) ^ ((uint32_t)(h & 7) << 4));
      *(uint16_t*)((char*)att_lds + off) = f2bf(acc[idx][r] * inv[r]);
    }
  }
  __syncthreads();  // att published

  // ---- att (bf16) -> global early; overlaps rv stream
#pragma unroll
  for (int i = 0; i < 4; ++i) {
    s16x8 vv = *(const s16x8*)((const char*)att_lds + i * 4096 + t * 16);
    *(s16x8*)((char*)SATT + (size_t)bm * 16384 + i * 4096 + t * 16) = vv;
  }
  asm volatile("" ::: "memory");

  // ---- rv stream: arv[h][rc] = sum_n att[h,n] * rv[n,rc]; wave-private, 2-deep
  f32x4 arv0 = (f32x4){0.f, 0.f, 0.f, 0.f}, arv1 = arv0;
#define RV_CONSUME(c)                                                          \
  {                                                                            \
    s16x8 a_ = *(const s16x8*)((const char*)att_lds + lr * 1024 +              \
               (((uint32_t)((c) * 64 + lg * 16)) ^ ((uint32_t)(lr & 7) << 4)));\
    const float* vb_ = (const float*)(wpriv + ((c) & 1) * 4096);               \
    s16x8 bf0_, bf1_;                                                          \
    _Pragma("unroll")                                                          \
    for (int i = 0; i < 8; ++i) bf0_[i] = (short)f2bf(vb_[(lg * 8 + i) * 32 + lr]); \
    _Pragma("unroll")                                                          \
    for (int i = 0; i < 8; ++i) bf1_[i] = (short)f2bf(vb_[(lg * 8 + i) * 32 + 16 + lr]); \
    arv0 = MFMA16(a_, bf0_, arv0);                                             \
    arv1 = MFMA16(a_, bf1_, arv1);                                             \
  }
#pragma unroll 1
  for (int c = 0; c < 14; ++c) {
    asm volatile("s_waitcnt vmcnt(4)" ::: "memory");
    RV_CONSUME(c)
#pragma unroll
    for (int g = 0; g < 4; ++g) {
      const char* src_ = rvb + (size_t)((c + 2) * 32 + g * 8 + r_lo) * 512 + w * 128 +
                         (lane & 7) * 16;
      gll16(src_, wpriv + ((c + 2) & 1) * 4096 + g * 1024 + lane * 16);
    }
  }
  asm volatile("s_waitcnt vmcnt(4)" ::: "memory");
  RV_CONSUME(14)
  asm volatile("s_waitcnt vmcnt(0)" ::: "memory");
  RV_CONSUME(15)

  // ---- arv -> LDS, val2 = arv @ Wrv + brv -> V2
#pragma unroll
  for (int r = 0; r < 4; ++r) {
    int h = lg * 4 + r;
    uint32_t rc0 = (uint32_t)(w * 32 + lr) * 2;
    uint32_t rc1 = (uint32_t)(w * 32 + 16 + lr) * 2;
    *(uint16_t*)((char*)arv_lds + h * 256 + (rc0 ^ ((uint32_t)(h & 7) << 4))) = f2bf(arv0[r]);
    *(uint16_t*)((char*)arv_lds + h * 256 + (rc1 ^ ((uint32_t)(h & 7) << 4))) = f2bf(arv1[r]);
  }
  __syncthreads();
  f32x4 vacc = (f32x4){0.f, 0.f, 0.f, 0.f};
#pragma unroll
  for (int kk = 0; kk < 4; ++kk) {
    uint32_t rb = (uint32_t)(kk * 32 + lg * 8) * 2;
    s16x8 a = *(const s16x8*)((const char*)arv_lds + lr * 256 +
                              (rb ^ ((uint32_t)(lr & 7) << 4)));
    s16x8 bfw = *(const s16x8*)(WrvT + (size_t)(w * 16 + lr) * 128 + kk * 32 + lg * 8);
    vacc = MFMA16(a, bfw, vacc);
  }
  float bias = brv[w * 16 + lr];
#pragma unroll
  for (int r = 0; r < 4; ++r)
    V2[(size_t)bm * 1024 + (lg * 4 + r) * 64 + w * 16 + lr] = f2bf(vacc[r] + bias);
}

// ---------------------------------------------------------------------------
// K4: val = att @ vh + V2 -> VALB. Grid (8,16,4); wave owns 16 m-rows.
// ---------------------------------------------------------------------------
__global__ __launch_bounds__(256) void k_val1(
    const uint16_t* __restrict__ vhT, const uint16_t* __restrict__ ATT,
    const uint16_t* __restrict__ V2, uint16_t* __restrict__ VALB) {
  int t = threadIdx.x, lane = t & 63, w = t >> 6, lr = lane & 15, lg = lane >> 4;
  int mt = blockIdx.x, h = blockIdx.y, b = blockIdx.z;
  int mb = mt * 64 + w * 16;
  const uint16_t* vrow = vhT + ((size_t)((b * 16 + h) * 64) + lr) * 512 + lg * 8;
  const uint16_t* arow = ATT + (size_t)(b * 512 + mb + lr) * 8192 + h * 512;
  f32x4 acc[4];
#pragma unroll
  for (int j = 0; j < 4; ++j) acc[j] = (f32x4){0.f, 0.f, 0.f, 0.f};
#pragma unroll 4
  for (int kk = 0; kk < 16; ++kk) {
    int nsw = (kk * 32 + lg * 8) ^ ((h & 7) << 3);
    s16x8 a0 = *(const s16x8*)(arow + nsw);
#pragma unroll
    for (int dt = 0; dt < 4; ++dt) {
      s16x8 vf = *(const s16x8*)(vrow + (size_t)dt * 16 * 512 + kk * 32);
      acc[dt] = MFMA16(vf, a0, acc[dt]);
    }
  }
#pragma unroll
  for (int dt = 0; dt < 4; ++dt) {
    size_t adr = (size_t)(b * 512 + mb + lr) * 1024 + h * 64 + dt * 16 + lg * 4;
    ushort4 v2v = *(const ushort4*)(V2 + adr);
    ushort4 o;
    o.x = f2bf(acc[dt][0] + bf2f(v2v.x));
    o.y = f2bf(acc[dt][1] + bf2f(v2v.y));
    o.z = f2bf(acc[dt][2] + bf2f(v2v.z));
    o.w = f2bf(acc[dt][3] + bf2f(v2v.w));
    *(ushort4*)(VALB + adr) = o;
  }
}

// ---------------------------------------------------------------------------
// K5: out = VAL @ Wo + bo (unchanged).
// ---------------------------------------------------------------------------
__global__ __launch_bounds__(256) void k_out(
    const uint16_t* __restrict__ A, const uint16_t* __restrict__ WT,
    const float* __restrict__ bias, float* __restrict__ out) {
  __shared__ alignas(16) uint16_t As[128 * 64];
  __shared__ alignas(16) uint16_t Bs[128 * 64];
  int t = threadIdx.x, lane = t & 63, w = t >> 6, lr = lane & 15, lg = lane >> 4;
  int m0 = blockIdx.x * 128, n0 = blockIdx.y * 128;
  int wm = (w >> 1) * 64, wn = (w & 1) * 64;
  f32x4 acc[4][4];
#pragma unroll
  for (int i = 0; i < 4; ++i)
#pragma unroll
    for (int j = 0; j < 4; ++j) acc[i][j] = (f32x4){0.f, 0.f, 0.f, 0.f};
  int srow = t >> 1, sh = t & 1;
  for (int ko = 0; ko < 16; ++ko) {
    __syncthreads();
    {
      const uint16_t* asrc = A + (size_t)(m0 + srow) * 1024 + ko * 64 + sh * 32;
      const uint16_t* bsrc = WT + (size_t)(n0 + srow) * 1024 + ko * 64 + sh * 32;
#pragma unroll
      for (int c = 0; c < 4; ++c) {
        s16x8 va = *(const s16x8*)(asrc + c * 8);
        *reinterpret_cast<s16x8*>((char*)As + srow * 128 +
                                  ((((sh * 4 + c) * 16)) ^ ((srow & 7) << 4))) = va;
        s16x8 vb = *(const s16x8*)(bsrc + c * 8);
        *reinterpret_cast<s16x8*>((char*)Bs + srow * 128 + (sh * 4 + c) * 16) = vb;
      }
    }
    __syncthreads();
#pragma unroll
    for (int kk = 0; kk < 2; ++kk) {
      s16x8 af[4], bf[4];
#pragma unroll
      for (int mt = 0; mt < 4; ++mt) {
        int row = wm + mt * 16 + lr;
        af[mt] = *(const s16x8*)((const char*)As + row * 128 +
                                 (((kk * 32 + lg * 8) * 2) ^ ((row & 7) << 4)));
      }
#pragma unroll
      for (int nt = 0; nt < 4; ++nt) {
        int row = wn + nt * 16 + lr;
        bf[nt] = *(const s16x8*)((const char*)Bs + row * 128 +
                                 (((kk * 32 + lg * 8) * 2) ^ ((row & 7) << 4)));
      }
#pragma unroll
      for (int mt = 0; mt < 4; ++mt)
#pragma unroll
        for (int nt = 0; nt < 4; ++nt)
          acc[mt][nt] = MFMA16(af[mt], bf[nt], acc[mt][nt]);
    }
  }
#pragma unroll
  for (int mt = 0; mt < 4; ++mt) {
#pragma unroll
    for (int nt = 0; nt < 4; ++nt) {
      int col = n0 + wn + nt * 16 + lr;
      float bcol = bias[col];
#pragma unroll
      for (int r = 0; r < 4; ++r) {
        int row = m0 + wm + mt * 16 + lg * 4 + r;
        out[(size_t)row * 1024 + col] = acc[mt][nt][r] + bcol;
      }
    }
  }
}

// ---------------------------------------------------------------------------
extern "C" void kernel_launch(void* const* d_in, const int* in_sizes, int n_in,
                              void* d_out, int out_size, void* d_ws, size_t ws_size,
                              hipStream_t stream) {
  const float* q   = (const float*)d_in[0];
  const float* k_  = (const float*)d_in[1];
  const float* v   = (const float*)d_in[2];
  const float* r_k = (const float*)d_in[3];
  const float* r_v = (const float*)d_in[4];
  const float* Wq  = (const float*)d_in[5];
  const float* bq  = (const float*)d_in[6];
  const float* Wk  = (const float*)d_in[7];
  const float* bk  = (const float*)d_in[8];
  const float* Wv  = (const float*)d_in[9];
  const float* bv  = (const float*)d_in[10];
  const float* Wrk = (const float*)d_in[11];
  // d_in[12] = brk: softmax-invariant, unused
  const float* Wrv = (const float*)d_in[13];
  const float* brv = (const float*)d_in[14];
  const float* Wo  = (const float*)d_in[15];
  const float* bo  = (const float*)d_in[16];
  (void)in_sizes; (void)n_in; (void)out_size;

  char* ws = (char*)d_ws;
  uint16_t* WqT  = (uint16_t*)(ws + (size_t)(0));
  uint16_t* WkT  = (uint16_t*)(ws + (size_t)(2u << 20));
  uint16_t* WvT  = (uint16_t*)(ws + (size_t)(4u << 20));
  uint16_t* WoT  = (uint16_t*)(ws + (size_t)(6u << 20));
  uint16_t* WrkB = (uint16_t*)(ws + (size_t)(8u << 20));
  uint16_t* WrvT = (uint16_t*)(ws + (size_t)(8u << 20) + (64u << 10));
  uint16_t* QH   = (uint16_t*)(ws + (size_t)(16u << 20));
  uint16_t* KH   = (uint16_t*)(ws + (size_t)(20u << 20));
  uint16_t* VHT  = (uint16_t*)(ws + (size_t)(24u << 20));
  uint16_t* QT   = (uint16_t*)(ws + (size_t)(28u << 20));
  uint16_t* VALB = (uint16_t*)(ws + (size_t)(36u << 20));
  uint16_t* V2   = (uint16_t*)(ws + (size_t)(16u << 20));  // QH slot, dead after score1
  uint16_t* SATT = (uint16_t*)(ws + (size_t)(40u << 20));  // 33.6 MB
  if (ws_size < (size_t)(74u << 20)) return;  // need 74 MB of scratch

  dim3 blk(256, 1, 1);
  k_prep<<<dim3(256, 5, 1), blk, 0, stream>>>(Wq, Wk, Wv, Wo, Wrk, Wrv,
                                              WqT, WkT, WvT, WoT, WrkB, WrvT);
  k_projqkv<<<dim3(16, 8, 3), blk, 0, stream>>>(q, k_, v, WqT, bq, bk, bv, QH);
  k_qt<<<dim3(512, 1, 1), blk, 0, stream>>>(QH, WrkB, QT);
  k_score1<<<dim3(8, 16, 4), blk, 0, stream>>>(QH, KH, SATT);
  k_s2v2<<<dim3(2048, 1, 1), blk, 0, stream>>>(QT, r_k, r_v, SATT, WrvT, brv, V2);
  k_val1<<<dim3(8, 16, 4), blk, 0, stream>>>(VHT, SATT, V2, VALB);
  k_out<<<dim3(16, 8, 1), blk, 0, stream>>>(VALB, WoT, bo, (float*)d_out);
}